// Round 13
// baseline (354.900 us; speedup 1.0000x reference)
//
#include <hip/hip_runtime.h>
#include <hip/hip_bf16.h>
#include <stdint.h>

#define NN 8192
#define FD 256
#define SLOPE 0.2f
#define LOG2E 1.44269504088896f

typedef float f32x4_t __attribute__((ext_vector_type(4)));
typedef __bf16 bf16x8_t __attribute__((ext_vector_type(8)));
typedef unsigned int u32x4_t __attribute__((ext_vector_type(4)));

__device__ __forceinline__ unsigned short f2bf(float x) {
  unsigned int u = __builtin_bit_cast(unsigned int, x);
  u += 0x7FFFu + ((u >> 16) & 1u);  // RNE
  return (unsigned short)(u >> 16);
}

__device__ __forceinline__ unsigned int cvtpk(float lo, float hi) {
  unsigned int r;
  asm("v_cvt_pk_bf16_f32 %0, %1, %2" : "=v"(r) : "v"(lo), "v"(hi));
  return r;
}

// ---------------- kernel 0: c1/c2[k] = sum_f W[f][k]*a{1,2}[f] ----------------
__global__ void gat_cvec(const float* __restrict__ W, const float* __restrict__ a,
                         float* __restrict__ c1, float* __restrict__ c2) {
  const int k = threadIdx.x;
  float acc1 = 0.f, acc2 = 0.f;
#pragma unroll 8
  for (int f = 0; f < FD; ++f) {
    float w = W[f * FD + k];
    acc1 = fmaf(w, a[f], acc1);
    acc2 = fmaf(w, a[FD + f], acc2);
  }
  c1[k] = acc1;
  c2[k] = acc2;
}

// ---- fused prep: blocks [0,512) wht | [512,2560) pack | [2560,4608) svec ----
__launch_bounds__(256)
__global__ void gat_prep(const float* __restrict__ h, const float* __restrict__ W,
                         const int* __restrict__ adj, const float* __restrict__ c1,
                         const float* __restrict__ c2,
                         unsigned short* __restrict__ whT2,
                         unsigned long long* __restrict__ mask64,
                         float* __restrict__ s1, float* __restrict__ s2) {
  __shared__ __align__(16) float hT[64][64];
  __shared__ __align__(16) float wT[64][64];
  const int b = blockIdx.x;
  const int t = threadIdx.x;

  if (b < 512) {
    const int i0 = (b & 127) * 64;
    const int f0 = (b >> 7) * 64;
    const int r = t & 63;
    const int kq = t >> 6;
    const int ty = t >> 4;
    const int tx = t & 15;
    float acc[4][4] = {};
    for (int k0 = 0; k0 < FD; k0 += 64) {
#pragma unroll
      for (int kk = 0; kk < 16; kk += 4) {
        float4 v = *(const float4*)(h + (size_t)(i0 + r) * FD + k0 + kq * 16 + kk);
        hT[kq * 16 + kk + 0][r] = v.x;
        hT[kq * 16 + kk + 1][r] = v.y;
        hT[kq * 16 + kk + 2][r] = v.z;
        hT[kq * 16 + kk + 3][r] = v.w;
        float4 u = *(const float4*)(W + (size_t)(f0 + r) * FD + k0 + kq * 16 + kk);
        wT[kq * 16 + kk + 0][r] = u.x;
        wT[kq * 16 + kk + 1][r] = u.y;
        wT[kq * 16 + kk + 2][r] = u.z;
        wT[kq * 16 + kk + 3][r] = u.w;
      }
      __syncthreads();
#pragma unroll 8
      for (int kk = 0; kk < 64; ++kk) {
        float4 av = *(const float4*)&hT[kk][ty * 4];
        float4 bv = *(const float4*)&wT[kk][tx * 4];
        acc[0][0] = fmaf(av.x, bv.x, acc[0][0]);
        acc[0][1] = fmaf(av.x, bv.y, acc[0][1]);
        acc[0][2] = fmaf(av.x, bv.z, acc[0][2]);
        acc[0][3] = fmaf(av.x, bv.w, acc[0][3]);
        acc[1][0] = fmaf(av.y, bv.x, acc[1][0]);
        acc[1][1] = fmaf(av.y, bv.y, acc[1][1]);
        acc[1][2] = fmaf(av.y, bv.z, acc[1][2]);
        acc[1][3] = fmaf(av.y, bv.w, acc[1][3]);
        acc[2][0] = fmaf(av.z, bv.x, acc[2][0]);
        acc[2][1] = fmaf(av.z, bv.y, acc[2][1]);
        acc[2][2] = fmaf(av.z, bv.z, acc[2][2]);
        acc[2][3] = fmaf(av.z, bv.w, acc[2][3]);
        acc[3][0] = fmaf(av.w, bv.x, acc[3][0]);
        acc[3][1] = fmaf(av.w, bv.y, acc[3][1]);
        acc[3][2] = fmaf(av.w, bv.z, acc[3][2]);
        acc[3][3] = fmaf(av.w, bv.w, acc[3][3]);
      }
      __syncthreads();
    }
    const int iv = i0 + ty * 4;
#pragma unroll
    for (int j = 0; j < 4; ++j) {
      const int f = f0 + tx * 4 + j;
      ushort4 o;
      o.x = f2bf(acc[0][j]);
      o.y = f2bf(acc[1][j]);
      o.z = f2bf(acc[2][j]);
      o.w = f2bf(acc[3][j]);
      *(ushort4*)(whT2 + (size_t)(iv >> 5) * (FD * 32) + (size_t)f * 32 + (iv & 31)) = o;
    }
  } else if (b < 2560) {
    const int vb = b - 512;
    const int lane = t & 63;
    const int w = t >> 6;
    const size_t ngroups = (size_t)NN * NN / 256;
    const size_t nw = (size_t)2048 * 4;
    for (size_t g = (size_t)vb * 4 + w; g < ngroups; g += nw) {
      const int* p = adj + g * 256 + lane;
      int v0 = p[0];
      int v1 = p[64];
      int v2 = p[128];
      int v3 = p[192];
      unsigned long long m0 = __ballot(v0 != 0);
      unsigned long long m1 = __ballot(v1 != 0);
      unsigned long long m2 = __ballot(v2 != 0);
      unsigned long long m3 = __ballot(v3 != 0);
      if (lane < 4) {
        unsigned long long mv = lane == 0 ? m0 : lane == 1 ? m1 : lane == 2 ? m2 : m3;
        mask64[g * 4 + lane] = mv;
      }
    }
  } else {
    const int i = (b - 2560) * 4 + (t >> 6);
    const int lane = t & 63;
    float4 hv = *(const float4*)(h + (size_t)i * FD + lane * 4);
    float4 u = *(const float4*)(c1 + lane * 4);
    float4 v = *(const float4*)(c2 + lane * 4);
    float d1 = hv.x * u.x + hv.y * u.y + hv.z * u.z + hv.w * u.w;
    float d2 = hv.x * v.x + hv.y * v.y + hv.z * v.z + hv.w * v.w;
#pragma unroll
    for (int m = 1; m < 64; m <<= 1) {
      d1 += __shfl_xor(d1, m, 64);
      d2 += __shfl_xor(d2, m, 64);
    }
    if (lane == 0) {
      s1[i] = d1 * LOG2E;
      s2[i] = d2 * LOG2E;
    }
  }
}

// ---- one MFMA A-fragment of P (8 cols): exp2 domain + v_cvt_pk_bf16_f32 -----
__device__ __forceinline__ bf16x8_t make_afrag(float s1r, const float4& slo,
                                               const float4& shi, unsigned int mbyte,
                                               float& lsum) {
  const float sv[8] = {slo.x, slo.y, slo.z, slo.w, shi.x, shi.y, shi.z, shi.w};
  float p[8];
#pragma unroll
  for (int c = 0; c < 8; ++c) {
    float x = s1r + sv[c];
    x = fmaxf(x, SLOPE * x);
    float pv = exp2f(x);
    p[c] = ((mbyte >> c) & 1u) ? pv : 0.f;
  }
  lsum += ((p[0] + p[1]) + (p[2] + p[3])) + ((p[4] + p[5]) + (p[6] + p[7]));
  u32x4_t w;
  w[0] = cvtpk(p[0], p[1]);
  w[1] = cvtpk(p[2], p[3]);
  w[2] = cvtpk(p[4], p[5]);
  w[3] = cvtpk(p[6], p[7]);
  return __builtin_bit_cast(bf16x8_t, w);
}

// -------- attention: 64-row waves (B shared via L1) + cross-iter B dbuf ------
// grid 256 = 64 rs x 4 kq. Block = 128 rows x 256 f x 2048 k; 8 waves =
// 2 rg x 2 fh x 2 ks2. Wave = 64 rows x 128 f x 1024 k, acc[4][8] (128 regs).
// rg-pair waves read IDENTICAL B addresses -> L1 hits (per-CU fresh B bytes
// 132->32 KB/iter-round). B register-double-buffered: iter t's MFMAs use B
// issued at t-1 (full-iter slack over L2 latency); sched_barrier-fenced,
// all-named registers (no runtime indexing). Barrier-free main loop.
__launch_bounds__(512, 2)
__global__ void gat_attn(const unsigned int* __restrict__ maskp,
                         const float* __restrict__ s1g, const float* __restrict__ s2g,
                         const unsigned short* __restrict__ whT2,
                         float* __restrict__ accP, float* __restrict__ lP) {
  __shared__ float red[4][64][129];  // ks2-merge staging, 132 KB (post-loop)
  __shared__ float lred[2][128];

  const int tid = threadIdx.x;
  const int lane = tid & 63;
  const int w = tid >> 6;
  const int rg = w & 1;
  const int fh = (w >> 1) & 1;
  const int ks2 = w >> 2;
  const int rs = blockIdx.x >> 2;
  const int kq = blockIdx.x & 3;
  const int kbase = kq * 2048 + ks2 * 1024;
  const int r16 = lane & 15;
  const int kg = lane >> 4;
  const int row0 = rs * 128 + rg * 64 + r16;

  const unsigned int* mrow0 = maskp + (size_t)row0 * (NN / 32) + (kbase >> 5);
  const unsigned int* mrow1 = mrow0 + (size_t)16 * (NN / 32);
  const unsigned int* mrow2 = mrow0 + (size_t)32 * (NN / 32);
  const unsigned int* mrow3 = mrow0 + (size_t)48 * (NN / 32);
  const float* s2p = s2g + kbase + kg * 8;
  // B base: ktile = kbase/32 + it; within tile: (fh*128 + ct*16 + r16)*32 + kg*8
  const unsigned short* bwave =
      whT2 + (size_t)(kbase >> 5) * 8192 + (fh * 128 + r16) * 32 + kg * 8;

  const float s1r0 = s1g[row0];
  const float s1r1 = s1g[row0 + 16];
  const float s1r2 = s1g[row0 + 32];
  const float s1r3 = s1g[row0 + 48];

  f32x4_t acc[4][8];
  const f32x4_t zero4 = {0.f, 0.f, 0.f, 0.f};
#pragma unroll
  for (int rt = 0; rt < 4; ++rt)
#pragma unroll
    for (int ct = 0; ct < 8; ++ct) acc[rt][ct] = zero4;

  float l0 = 0.f, l1 = 0.f, l2 = 0.f, l3 = 0.f;

  // ---- prologue: B(0) -> c-set; masks/s2(0) ----
  bf16x8_t c0 = *(const bf16x8_t*)(bwave + 0 * 512);
  bf16x8_t c1 = *(const bf16x8_t*)(bwave + 1 * 512);
  bf16x8_t c2 = *(const bf16x8_t*)(bwave + 2 * 512);
  bf16x8_t c3 = *(const bf16x8_t*)(bwave + 3 * 512);
  bf16x8_t c4 = *(const bf16x8_t*)(bwave + 4 * 512);
  bf16x8_t c5 = *(const bf16x8_t*)(bwave + 5 * 512);
  bf16x8_t c6 = *(const bf16x8_t*)(bwave + 6 * 512);
  bf16x8_t c7 = *(const bf16x8_t*)(bwave + 7 * 512);
  bf16x8_t n0, n1, n2, n3, n4, n5, n6, n7;
  unsigned int cm0 = mrow0[0], cm1 = mrow1[0], cm2 = mrow2[0], cm3 = mrow3[0];
  unsigned int nm0, nm1, nm2, nm3;
  float4 csl = *(const float4*)(s2p);
  float4 csh = *(const float4*)(s2p + 4);
  float4 nsl, nsh;

#define GAT_ITER(IT, B0, B1, B2, B3, B4, B5, B6, B7, X0, X1, X2, X3, X4, X5, X6, X7) \
  {                                                                                   \
    const int itn_ = ((IT) + 1 < 32) ? (IT) + 1 : (IT);                               \
    const unsigned short* bn_ = bwave + (size_t)itn_ * 8192;                          \
    X0 = *(const bf16x8_t*)(bn_ + 0 * 512);                                           \
    X1 = *(const bf16x8_t*)(bn_ + 1 * 512);                                           \
    X2 = *(const bf16x8_t*)(bn_ + 2 * 512);                                           \
    X3 = *(const bf16x8_t*)(bn_ + 3 * 512);                                           \
    X4 = *(const bf16x8_t*)(bn_ + 4 * 512);                                           \
    X5 = *(const bf16x8_t*)(bn_ + 5 * 512);                                           \
    X6 = *(const bf16x8_t*)(bn_ + 6 * 512);                                           \
    X7 = *(const bf16x8_t*)(bn_ + 7 * 512);                                           \
    nm0 = mrow0[itn_];                                                                \
    nm1 = mrow1[itn_];                                                                \
    nm2 = mrow2[itn_];                                                                \
    nm3 = mrow3[itn_];                                                                \
    nsl = *(const float4*)(s2p + itn_ * 32);                                          \
    nsh = *(const float4*)(s2p + itn_ * 32 + 4);                                      \
    __builtin_amdgcn_sched_barrier(0);                                                \
    bf16x8_t af0 = make_afrag(s1r0, csl, csh, (cm0 >> (kg * 8)) & 0xffu, l0);         \
    bf16x8_t af1 = make_afrag(s1r1, csl, csh, (cm1 >> (kg * 8)) & 0xffu, l1);         \
    bf16x8_t af2 = make_afrag(s1r2, csl, csh, (cm2 >> (kg * 8)) & 0xffu, l2);         \
    bf16x8_t af3 = make_afrag(s1r3, csl, csh, (cm3 >> (kg * 8)) & 0xffu, l3);         \
    __builtin_amdgcn_sched_barrier(0);                                                \
    acc[0][0] = __builtin_amdgcn_mfma_f32_16x16x32_bf16(af0, B0, acc[0][0], 0, 0, 0); \
    acc[1][0] = __builtin_amdgcn_mfma_f32_16x16x32_bf16(af1, B0, acc[1][0], 0, 0, 0); \
    acc[2][0] = __builtin_amdgcn_mfma_f32_16x16x32_bf16(af2, B0, acc[2][0], 0, 0, 0); \
    acc[3][0] = __builtin_amdgcn_mfma_f32_16x16x32_bf16(af3, B0, acc[3][0], 0, 0, 0); \
    acc[0][1] = __builtin_amdgcn_mfma_f32_16x16x32_bf16(af0, B1, acc[0][1], 0, 0, 0); \
    acc[1][1] = __builtin_amdgcn_mfma_f32_16x16x32_bf16(af1, B1, acc[1][1], 0, 0, 0); \
    acc[2][1] = __builtin_amdgcn_mfma_f32_16x16x32_bf16(af2, B1, acc[2][1], 0, 0, 0); \
    acc[3][1] = __builtin_amdgcn_mfma_f32_16x16x32_bf16(af3, B1, acc[3][1], 0, 0, 0); \
    acc[0][2] = __builtin_amdgcn_mfma_f32_16x16x32_bf16(af0, B2, acc[0][2], 0, 0, 0); \
    acc[1][2] = __builtin_amdgcn_mfma_f32_16x16x32_bf16(af1, B2, acc[1][2], 0, 0, 0); \
    acc[2][2] = __builtin_amdgcn_mfma_f32_16x16x32_bf16(af2, B2, acc[2][2], 0, 0, 0); \
    acc[3][2] = __builtin_amdgcn_mfma_f32_16x16x32_bf16(af3, B2, acc[3][2], 0, 0, 0); \
    acc[0][3] = __builtin_amdgcn_mfma_f32_16x16x32_bf16(af0, B3, acc[0][3], 0, 0, 0); \
    acc[1][3] = __builtin_amdgcn_mfma_f32_16x16x32_bf16(af1, B3, acc[1][3], 0, 0, 0); \
    acc[2][3] = __builtin_amdgcn_mfma_f32_16x16x32_bf16(af2, B3, acc[2][3], 0, 0, 0); \
    acc[3][3] = __builtin_amdgcn_mfma_f32_16x16x32_bf16(af3, B3, acc[3][3], 0, 0, 0); \
    acc[0][4] = __builtin_amdgcn_mfma_f32_16x16x32_bf16(af0, B4, acc[0][4], 0, 0, 0); \
    acc[1][4] = __builtin_amdgcn_mfma_f32_16x16x32_bf16(af1, B4, acc[1][4], 0, 0, 0); \
    acc[2][4] = __builtin_amdgcn_mfma_f32_16x16x32_bf16(af2, B4, acc[2][4], 0, 0, 0); \
    acc[3][4] = __builtin_amdgcn_mfma_f32_16x16x32_bf16(af3, B4, acc[3][4], 0, 0, 0); \
    acc[0][5] = __builtin_amdgcn_mfma_f32_16x16x32_bf16(af0, B5, acc[0][5], 0, 0, 0); \
    acc[1][5] = __builtin_amdgcn_mfma_f32_16x16x32_bf16(af1, B5, acc[1][5], 0, 0, 0); \
    acc[2][5] = __builtin_amdgcn_mfma_f32_16x16x32_bf16(af2, B5, acc[2][5], 0, 0, 0); \
    acc[3][5] = __builtin_amdgcn_mfma_f32_16x16x32_bf16(af3, B5, acc[3][5], 0, 0, 0); \
    acc[0][6] = __builtin_amdgcn_mfma_f32_16x16x32_bf16(af0, B6, acc[0][6], 0, 0, 0); \
    acc[1][6] = __builtin_amdgcn_mfma_f32_16x16x32_bf16(af1, B6, acc[1][6], 0, 0, 0); \
    acc[2][6] = __builtin_amdgcn_mfma_f32_16x16x32_bf16(af2, B6, acc[2][6], 0, 0, 0); \
    acc[3][6] = __builtin_amdgcn_mfma_f32_16x16x32_bf16(af3, B6, acc[3][6], 0, 0, 0); \
    acc[0][7] = __builtin_amdgcn_mfma_f32_16x16x32_bf16(af0, B7, acc[0][7], 0, 0, 0); \
    acc[1][7] = __builtin_amdgcn_mfma_f32_16x16x32_bf16(af1, B7, acc[1][7], 0, 0, 0); \
    acc[2][7] = __builtin_amdgcn_mfma_f32_16x16x32_bf16(af2, B7, acc[2][7], 0, 0, 0); \
    acc[3][7] = __builtin_amdgcn_mfma_f32_16x16x32_bf16(af3, B7, acc[3][7], 0, 0, 0); \
    __builtin_amdgcn_sched_barrier(0);                                                \
    cm0 = nm0;                                                                        \
    cm1 = nm1;                                                                        \
    cm2 = nm2;                                                                        \
    cm3 = nm3;                                                                        \
    csl = nsl;                                                                        \
    csh = nsh;                                                                        \
  }

  for (int itp = 0; itp < 16; ++itp) {
    const int it0 = itp * 2;
    GAT_ITER(it0, c0, c1, c2, c3, c4, c5, c6, c7, n0, n1, n2, n3, n4, n5, n6, n7)
    GAT_ITER(it0 + 1, n0, n1, n2, n3, n4, n5, n6, n7, c0, c1, c2, c3, c4, c5, c6, c7)
  }
#undef GAT_ITER

  // ---- l: reduce over kg lane-groups ----
  l0 += __shfl_xor(l0, 16, 64);
  l0 += __shfl_xor(l0, 32, 64);
  l1 += __shfl_xor(l1, 16, 64);
  l1 += __shfl_xor(l1, 32, 64);
  l2 += __shfl_xor(l2, 16, 64);
  l2 += __shfl_xor(l2, 32, 64);
  l3 += __shfl_xor(l3, 16, 64);
  l3 += __shfl_xor(l3, 32, 64);
  if (fh == 0 && lane < 16) {
    lred[ks2][rg * 64 + r16] = l0;
    lred[ks2][rg * 64 + 16 + r16] = l1;
    lred[ks2][rg * 64 + 32 + r16] = l2;
    lred[ks2][rg * 64 + 48 + r16] = l3;
  }

  // ---- acc: ks2=1 stages to LDS; ks2=0 adds + writes accP[kq] ----
  if (ks2 == 1) {
#pragma unroll
    for (int rt = 0; rt < 4; ++rt)
#pragma unroll
      for (int ct = 0; ct < 8; ++ct) {
        const int col = ct * 16 + r16;
#pragma unroll
        for (int g = 0; g < 4; ++g)
          red[rg * 2 + fh][rt * 16 + kg * 4 + g][col] = acc[rt][ct][g];
      }
  }
  __syncthreads();
  if (ks2 == 0) {
    float* ap = accP + (size_t)kq * NN * FD + (size_t)(rs * 128 + rg * 64) * FD + fh * 128;
#pragma unroll
    for (int rt = 0; rt < 4; ++rt)
#pragma unroll
      for (int ct = 0; ct < 8; ++ct) {
        const int col = ct * 16 + r16;
#pragma unroll
        for (int g = 0; g < 4; ++g) {
          const int rl = rt * 16 + kg * 4 + g;
          ap[(size_t)rl * FD + col] = acc[rt][ct][g] + red[rg * 2 + fh][rl][col];
        }
      }
  }
  if (tid < 128) {
    lP[(size_t)kq * NN + rs * 128 + tid] = lred[0][tid] + lred[1][tid];
  }
}

// ---------------- merge: out[i][f] = sum_kq accP / sum_kq lP -----------------
__global__ void gat_merge(const float* __restrict__ accP, const float* __restrict__ lP,
                          float* __restrict__ out) {
  const int i = blockIdx.x;
  const int f = threadIdx.x;
  float s = 0.f, l = 0.f;
#pragma unroll
  for (int q = 0; q < 4; ++q) {
    s += accP[((size_t)q * NN + i) * FD + f];
    l += lP[(size_t)q * NN + i];
  }
  out[(size_t)i * FD + f] = s / l;
}

extern "C" void kernel_launch(void* const* d_in, const int* in_sizes, int n_in,
                              void* d_out, int out_size, void* d_ws, size_t ws_size,
                              hipStream_t stream) {
  const float* h = (const float*)d_in[0];
  const int* adj = (const int*)d_in[1];
  const float* W = (const float*)d_in[2];
  const float* a = (const float*)d_in[3];
  float* out = (float*)d_out;

  char* ws = (char*)d_ws;
  unsigned short* whT2 = (unsigned short*)ws;                        // 4 MB
  float* s1 = (float*)(ws + 4194304);                                // 32 KB
  float* s2 = (float*)(ws + 4194304 + 32768);                        // 32 KB
  float* c1 = (float*)(ws + 4194304 + 65536);                        // 1 KB
  float* c2 = (float*)(ws + 4194304 + 65536 + 1024);                 // 1 KB
  unsigned long long* mask64 = (unsigned long long*)(ws + 5242880);  // 8 MB
  float* accP = (float*)(ws + 16777216);                             // 32 MB
  float* lP = (float*)(ws + 50331648);                               // 128 KB

  gat_cvec<<<1, 256, 0, stream>>>(W, a, c1, c2);
  gat_prep<<<4608, 256, 0, stream>>>(h, W, adj, c1, c2, whT2, mask64, s1, s2);
  gat_attn<<<256, 512, 0, stream>>>((const unsigned int*)mask64, s1, s2, whT2, accP, lP);
  gat_merge<<<NN, FD, 0, stream>>>(accP, lP, out);
}

// Round 14
// 186.722 us; speedup vs baseline: 1.9007x; 1.9007x over previous
//
#include <hip/hip_runtime.h>
#include <hip/hip_bf16.h>
#include <stdint.h>

#define NN 8192
#define FD 256
#define SLOPE 0.2f
#define LOG2E 1.44269504088896f

typedef float f32x4_t __attribute__((ext_vector_type(4)));
typedef __bf16 bf16x8_t __attribute__((ext_vector_type(8)));
typedef unsigned int u32x4_t __attribute__((ext_vector_type(4)));

__device__ __forceinline__ unsigned short f2bf(float x) {
  unsigned int u = __builtin_bit_cast(unsigned int, x);
  u += 0x7FFFu + ((u >> 16) & 1u);  // RNE
  return (unsigned short)(u >> 16);
}

__device__ __forceinline__ unsigned int cvtpk(float lo, float hi) {
  unsigned int r;
  asm("v_cvt_pk_bf16_f32 %0, %1, %2" : "=v"(r) : "v"(lo), "v"(hi));
  return r;
}

__device__ __forceinline__ void gload_lds16(const void* g, void* l) {
  __builtin_amdgcn_global_load_lds(
      (const __attribute__((address_space(1))) uint32_t*)g,
      (__attribute__((address_space(3))) uint32_t*)l, 16, 0, 0);
}

// ---------------- kernel 0: c1/c2[k] = sum_f W[f][k]*a{1,2}[f] ----------------
__global__ void gat_cvec(const float* __restrict__ W, const float* __restrict__ a,
                         float* __restrict__ c1, float* __restrict__ c2) {
  const int k = threadIdx.x;
  float acc1 = 0.f, acc2 = 0.f;
#pragma unroll 8
  for (int f = 0; f < FD; ++f) {
    float w = W[f * FD + k];
    acc1 = fmaf(w, a[f], acc1);
    acc2 = fmaf(w, a[FD + f], acc2);
  }
  c1[k] = acc1;
  c2[k] = acc2;
}

// ---- fused prep: blocks [0,512) wht | [512,2560) pack | [2560,4608) svec ----
// wht now stores whTK[ktile(64k)][f(256)][k%64] with the G4 XOR swizzle
// PRE-APPLIED: short idx = ktile*16384 + f*64 + ((k>>3)^(f&7))*8 + (k&7).
// (rule #21: gload_lds dest is linear, so the source carries the swizzle.)
__launch_bounds__(256)
__global__ void gat_prep(const float* __restrict__ h, const float* __restrict__ W,
                         const int* __restrict__ adj, const float* __restrict__ c1,
                         const float* __restrict__ c2,
                         unsigned short* __restrict__ whTK,
                         unsigned long long* __restrict__ mask64,
                         float* __restrict__ s1, float* __restrict__ s2) {
  __shared__ __align__(16) float hT[64][64];
  __shared__ __align__(16) float wT[64][64];
  const int b = blockIdx.x;
  const int t = threadIdx.x;

  if (b < 512) {
    const int i0 = (b & 127) * 64;  // k-range (rows of Wh)
    const int f0 = (b >> 7) * 64;
    const int r = t & 63;
    const int kq = t >> 6;
    const int ty = t >> 4;
    const int tx = t & 15;
    float acc[4][4] = {};
    for (int k0 = 0; k0 < FD; k0 += 64) {
#pragma unroll
      for (int kk = 0; kk < 16; kk += 4) {
        float4 v = *(const float4*)(h + (size_t)(i0 + r) * FD + k0 + kq * 16 + kk);
        hT[kq * 16 + kk + 0][r] = v.x;
        hT[kq * 16 + kk + 1][r] = v.y;
        hT[kq * 16 + kk + 2][r] = v.z;
        hT[kq * 16 + kk + 3][r] = v.w;
        float4 u = *(const float4*)(W + (size_t)(f0 + r) * FD + k0 + kq * 16 + kk);
        wT[kq * 16 + kk + 0][r] = u.x;
        wT[kq * 16 + kk + 1][r] = u.y;
        wT[kq * 16 + kk + 2][r] = u.z;
        wT[kq * 16 + kk + 3][r] = u.w;
      }
      __syncthreads();
#pragma unroll 8
      for (int kk = 0; kk < 64; ++kk) {
        float4 av = *(const float4*)&hT[kk][ty * 4];
        float4 bv = *(const float4*)&wT[kk][tx * 4];
        acc[0][0] = fmaf(av.x, bv.x, acc[0][0]);
        acc[0][1] = fmaf(av.x, bv.y, acc[0][1]);
        acc[0][2] = fmaf(av.x, bv.z, acc[0][2]);
        acc[0][3] = fmaf(av.x, bv.w, acc[0][3]);
        acc[1][0] = fmaf(av.y, bv.x, acc[1][0]);
        acc[1][1] = fmaf(av.y, bv.y, acc[1][1]);
        acc[1][2] = fmaf(av.y, bv.z, acc[1][2]);
        acc[1][3] = fmaf(av.y, bv.w, acc[1][3]);
        acc[2][0] = fmaf(av.z, bv.x, acc[2][0]);
        acc[2][1] = fmaf(av.z, bv.y, acc[2][1]);
        acc[2][2] = fmaf(av.z, bv.z, acc[2][2]);
        acc[2][3] = fmaf(av.z, bv.w, acc[2][3]);
        acc[3][0] = fmaf(av.w, bv.x, acc[3][0]);
        acc[3][1] = fmaf(av.w, bv.y, acc[3][1]);
        acc[3][2] = fmaf(av.w, bv.z, acc[3][2]);
        acc[3][3] = fmaf(av.w, bv.w, acc[3][3]);
      }
      __syncthreads();
    }
    const int iv = i0 + ty * 4;      // k, multiple of 4
    const int ktile = iv >> 6;
    const int kl = iv & 63;          // k within tile; kl&7 in {0,4}
#pragma unroll
    for (int j = 0; j < 4; ++j) {
      const int f = f0 + tx * 4 + j;
      ushort4 o;
      o.x = f2bf(acc[0][j]);
      o.y = f2bf(acc[1][j]);
      o.z = f2bf(acc[2][j]);
      o.w = f2bf(acc[3][j]);
      const size_t idx = (size_t)ktile * 16384 + (size_t)f * 64 +
                         (size_t)(((kl >> 3) ^ (f & 7)) * 8 + (kl & 7));
      *(ushort4*)(whTK + idx) = o;
    }
  } else if (b < 2560) {
    const int vb = b - 512;
    const int lane = t & 63;
    const int w = t >> 6;
    const size_t ngroups = (size_t)NN * NN / 256;
    const size_t nw = (size_t)2048 * 4;
    for (size_t g = (size_t)vb * 4 + w; g < ngroups; g += nw) {
      const int* p = adj + g * 256 + lane;
      int v0 = p[0];
      int v1 = p[64];
      int v2 = p[128];
      int v3 = p[192];
      unsigned long long m0 = __ballot(v0 != 0);
      unsigned long long m1 = __ballot(v1 != 0);
      unsigned long long m2 = __ballot(v2 != 0);
      unsigned long long m3 = __ballot(v3 != 0);
      if (lane < 4) {
        unsigned long long mv = lane == 0 ? m0 : lane == 1 ? m1 : lane == 2 ? m2 : m3;
        mask64[g * 4 + lane] = mv;
      }
    }
  } else {
    const int i = (b - 2560) * 4 + (t >> 6);
    const int lane = t & 63;
    float4 hv = *(const float4*)(h + (size_t)i * FD + lane * 4);
    float4 u = *(const float4*)(c1 + lane * 4);
    float4 v = *(const float4*)(c2 + lane * 4);
    float d1 = hv.x * u.x + hv.y * u.y + hv.z * u.z + hv.w * u.w;
    float d2 = hv.x * v.x + hv.y * v.y + hv.z * v.z + hv.w * v.w;
#pragma unroll
    for (int m = 1; m < 64; m <<= 1) {
      d1 += __shfl_xor(d1, m, 64);
      d2 += __shfl_xor(d2, m, 64);
    }
    if (lane == 0) {
      s1[i] = d1 * LOG2E;
      s2[i] = d2 * LOG2E;
    }
  }
}

// ------------- attention: m97-structure GEMM, P computed into LDS ------------
// grid 1024 = 64 rs x 2 fh x 8 kq; block 256 thr = 4 waves. Block output:
// 128 rows x 128 f over a 1024-k slice; 16 iters of BK=64.
// Per iter: [stage B(it+1) via 16 gload_lds, dbuf] [P-VALU: 1 row x 32 k per
// thread from ONE mask word + LDS-broadcast s2 -> ds_write_b128 x4 into
// XOR-swizzled A-tile] barrier [16 ds_read_b128 + 32 MFMA per wave] barrier.
// No manual waitcnt/sched_barrier: m97's compiler-scheduled pattern.
// LDS = 32 KB B-dbuf + 16 KB A + 4 KB s2 = 52 KB -> 3 blocks/CU.
__launch_bounds__(256, 3)
__global__ void gat_attn(const unsigned int* __restrict__ maskp,
                         const float* __restrict__ s1g, const float* __restrict__ s2g,
                         const unsigned short* __restrict__ whTK,
                         float* __restrict__ accP, float* __restrict__ lP) {
  __shared__ __align__(16) unsigned short Bs[2][64 * 128];  // [buf][f][k] swz, 32 KB
  __shared__ __align__(16) unsigned short As[128 * 64];     // [row][k] swz, 16 KB
  __shared__ __align__(16) float s2s[1024];                 // 4 KB; reused as lred

  const int tid = threadIdx.x;
  const int lane = tid & 63;
  const int w = tid >> 6;
  const int kq = blockIdx.x & 7;
  const int fh = (blockIdx.x >> 3) & 1;
  const int rs = blockIdx.x >> 4;
  const int kbase = kq * 1024;

  // P-phase role: row tr, 32-k half kh
  const int tr = tid & 127;
  const int kh = tid >> 7;
  const float s1r = s1g[rs * 128 + tr];
  const unsigned int* mrow = maskp + (size_t)(rs * 128 + tr) * (NN / 32) + (kbase >> 5) + kh;

  // MFMA-phase role
  const int wr = w & 1;
  const int wc = w >> 1;
  const int r16 = lane & 15;
  const int kg = lane >> 4;

  // stage s2 tile (whole block k-range)
  *(float4*)&s2s[tid * 4] = *(const float4*)(s2g + kbase + tid * 4);

  // prologue: stage B(0)
  {
    const char* bsrc = (const char*)whTK + (size_t)(kq * 16) * 32768 + fh * 16384;
    char* bdst = (char*)Bs[0];
#pragma unroll
    for (int q = 0; q < 4; ++q)
      gload_lds16(bsrc + w * 4096 + q * 1024 + lane * 16, bdst + w * 4096 + q * 1024);
  }
  unsigned int mw = mrow[0];
  float l_acc = 0.f;

  f32x4_t acc[4][4];
  const f32x4_t zero4 = {0.f, 0.f, 0.f, 0.f};
#pragma unroll
  for (int rt = 0; rt < 4; ++rt)
#pragma unroll
    for (int ct = 0; ct < 4; ++ct) acc[rt][ct] = zero4;

  __syncthreads();  // s2s + B(0) ready

  for (int it = 0; it < 16; ++it) {
    // ---- stage B(it+1) into the other buffer ----
    if (it + 1 < 16) {
      const char* bsrc =
          (const char*)whTK + (size_t)(kq * 16 + it + 1) * 32768 + fh * 16384;
      char* bdst = (char*)Bs[(it + 1) & 1];
#pragma unroll
      for (int q = 0; q < 4; ++q)
        gload_lds16(bsrc + w * 4096 + q * 1024 + lane * 16, bdst + w * 4096 + q * 1024);
    }

    // ---- P-phase: 32 entries (1 row x 32 k), ds_write into swizzled A ----
    {
      const int kloc = it * 64 + kh * 32;
#pragma unroll
      for (int c = 0; c < 4; ++c) {
        float4 sa = *(const float4*)&s2s[kloc + c * 8];      // broadcast
        float4 sb = *(const float4*)&s2s[kloc + c * 8 + 4];  // broadcast
        const float sv[8] = {sa.x, sa.y, sa.z, sa.w, sb.x, sb.y, sb.z, sb.w};
        float p[8];
#pragma unroll
        for (int e = 0; e < 8; ++e) {
          float x = s1r + sv[e];
          x = fmaxf(x, SLOPE * x);
          float pv = exp2f(x);
          p[e] = ((mw >> (c * 8 + e)) & 1u) ? pv : 0.f;
        }
        l_acc += ((p[0] + p[1]) + (p[2] + p[3])) + ((p[4] + p[5]) + (p[6] + p[7]));
        u32x4_t wv;
        wv[0] = cvtpk(p[0], p[1]);
        wv[1] = cvtpk(p[2], p[3]);
        wv[2] = cvtpk(p[4], p[5]);
        wv[3] = cvtpk(p[6], p[7]);
        const int chunk = (kh * 4 + c) ^ (tr & 7);
        *(u32x4_t*)((char*)As + tr * 128 + chunk * 16) = wv;  // ds_write_b128
      }
    }
    // next iter's mask word (in flight until next barrier-2)
    unsigned int mwn = (it + 1 < 16) ? mrow[(it + 1) * 2] : 0u;

    __syncthreads();  // A(it) + B(it+1) landed; B(it) staged last iter

    // ---- MFMA phase: frags from LDS, 32 MFMA ----
    {
      const unsigned short* bb = Bs[it & 1];
#pragma unroll
      for (int kc = 0; kc < 2; ++kc) {
        bf16x8_t a0, a1, a2, a3, b0, b1, b2, b3;
        {
          const int row0 = wr * 64 + r16;
          const int ch = kc * 4 + kg;
          a0 = *(const bf16x8_t*)((const char*)As + (row0 + 0) * 128 + ((ch ^ ((row0 + 0) & 7)) * 16));
          a1 = *(const bf16x8_t*)((const char*)As + (row0 + 16) * 128 + ((ch ^ ((row0 + 16) & 7)) * 16));
          a2 = *(const bf16x8_t*)((const char*)As + (row0 + 32) * 128 + ((ch ^ ((row0 + 32) & 7)) * 16));
          a3 = *(const bf16x8_t*)((const char*)As + (row0 + 48) * 128 + ((ch ^ ((row0 + 48) & 7)) * 16));
          const int f0l = wc * 64 + r16;
          b0 = *(const bf16x8_t*)((const char*)bb + (f0l + 0) * 128 + ((ch ^ ((f0l + 0) & 7)) * 16));
          b1 = *(const bf16x8_t*)((const char*)bb + (f0l + 16) * 128 + ((ch ^ ((f0l + 16) & 7)) * 16));
          b2 = *(const bf16x8_t*)((const char*)bb + (f0l + 32) * 128 + ((ch ^ ((f0l + 32) & 7)) * 16));
          b3 = *(const bf16x8_t*)((const char*)bb + (f0l + 48) * 128 + ((ch ^ ((f0l + 48) & 7)) * 16));
        }
        acc[0][0] = __builtin_amdgcn_mfma_f32_16x16x32_bf16(a0, b0, acc[0][0], 0, 0, 0);
        acc[0][1] = __builtin_amdgcn_mfma_f32_16x16x32_bf16(a0, b1, acc[0][1], 0, 0, 0);
        acc[0][2] = __builtin_amdgcn_mfma_f32_16x16x32_bf16(a0, b2, acc[0][2], 0, 0, 0);
        acc[0][3] = __builtin_amdgcn_mfma_f32_16x16x32_bf16(a0, b3, acc[0][3], 0, 0, 0);
        acc[1][0] = __builtin_amdgcn_mfma_f32_16x16x32_bf16(a1, b0, acc[1][0], 0, 0, 0);
        acc[1][1] = __builtin_amdgcn_mfma_f32_16x16x32_bf16(a1, b1, acc[1][1], 0, 0, 0);
        acc[1][2] = __builtin_amdgcn_mfma_f32_16x16x32_bf16(a1, b2, acc[1][2], 0, 0, 0);
        acc[1][3] = __builtin_amdgcn_mfma_f32_16x16x32_bf16(a1, b3, acc[1][3], 0, 0, 0);
        acc[2][0] = __builtin_amdgcn_mfma_f32_16x16x32_bf16(a2, b0, acc[2][0], 0, 0, 0);
        acc[2][1] = __builtin_amdgcn_mfma_f32_16x16x32_bf16(a2, b1, acc[2][1], 0, 0, 0);
        acc[2][2] = __builtin_amdgcn_mfma_f32_16x16x32_bf16(a2, b2, acc[2][2], 0, 0, 0);
        acc[2][3] = __builtin_amdgcn_mfma_f32_16x16x32_bf16(a2, b3, acc[2][3], 0, 0, 0);
        acc[3][0] = __builtin_amdgcn_mfma_f32_16x16x32_bf16(a3, b0, acc[3][0], 0, 0, 0);
        acc[3][1] = __builtin_amdgcn_mfma_f32_16x16x32_bf16(a3, b1, acc[3][1], 0, 0, 0);
        acc[3][2] = __builtin_amdgcn_mfma_f32_16x16x32_bf16(a3, b2, acc[3][2], 0, 0, 0);
        acc[3][3] = __builtin_amdgcn_mfma_f32_16x16x32_bf16(a3, b3, acc[3][3], 0, 0, 0);
      }
    }
    __syncthreads();  // tiles consumed; safe to rewrite next iter
    mw = mwn;
  }

  // ---- l partials (s2s reused as lred[2][128]) ----
  float* lred = s2s;
  lred[kh * 128 + tr] = l_acc;
  __syncthreads();
  if (tid < 128)
    lP[(size_t)kq * NN + rs * 128 + tid] = lred[tid] + lred[128 + tid];

  // ---- acc partials ----
  float* ap = accP + (size_t)kq * NN * FD;
#pragma unroll
  for (int rt = 0; rt < 4; ++rt) {
#pragma unroll
    for (int ct = 0; ct < 4; ++ct) {
      const int col = fh * 128 + wc * 64 + ct * 16 + r16;
#pragma unroll
      for (int g = 0; g < 4; ++g) {
        const int row = rs * 128 + wr * 64 + rt * 16 + kg * 4 + g;
        ap[(size_t)row * FD + col] = acc[rt][ct][g];
      }
    }
  }
}

// ---------------- merge: out[i][f] = sum_kq accP / sum_kq lP -----------------
__global__ void gat_merge(const float* __restrict__ accP, const float* __restrict__ lP,
                          float* __restrict__ out) {
  const int i = blockIdx.x;
  const int f = threadIdx.x;
  float s = 0.f, l = 0.f;
#pragma unroll
  for (int q = 0; q < 8; ++q) {
    s += accP[((size_t)q * NN + i) * FD + f];
    l += lP[(size_t)q * NN + i];
  }
  out[(size_t)i * FD + f] = s / l;
}

extern "C" void kernel_launch(void* const* d_in, const int* in_sizes, int n_in,
                              void* d_out, int out_size, void* d_ws, size_t ws_size,
                              hipStream_t stream) {
  const float* h = (const float*)d_in[0];
  const int* adj = (const int*)d_in[1];
  const float* W = (const float*)d_in[2];
  const float* a = (const float*)d_in[3];
  float* out = (float*)d_out;

  char* ws = (char*)d_ws;
  unsigned short* whTK = (unsigned short*)ws;                        // 4 MB
  float* s1 = (float*)(ws + 4194304);                                // 32 KB
  float* s2 = (float*)(ws + 4194304 + 32768);                        // 32 KB
  float* c1 = (float*)(ws + 4194304 + 65536);                        // 1 KB
  float* c2 = (float*)(ws + 4194304 + 65536 + 1024);                 // 1 KB
  unsigned long long* mask64 = (unsigned long long*)(ws + 5242880);  // 8 MB
  float* accP = (float*)(ws + 16777216);                             // 8 x 8 MB
  float* lP = (float*)(ws + 16777216 + 8ull * NN * FD * 4);          // 256 KB

  gat_cvec<<<1, 256, 0, stream>>>(W, a, c1, c2);
  gat_prep<<<4608, 256, 0, stream>>>(h, W, adj, c1, c2, whTK, mask64, s1, s2);
  gat_attn<<<1024, 256, 0, stream>>>((const unsigned int*)mask64, s1, s2, whTK, accP, lP);
  gat_merge<<<NN, FD, 0, stream>>>(accP, lP, out);
}

// Round 15
// 168.686 us; speedup vs baseline: 2.1039x; 1.1069x over previous
//
#include <hip/hip_runtime.h>
#include <hip/hip_bf16.h>
#include <stdint.h>

#define NN 8192
#define FD 256
#define SLOPE 0.2f
#define LOG2E 1.44269504088896f

typedef float f32x4_t __attribute__((ext_vector_type(4)));
typedef __bf16 bf16x8_t __attribute__((ext_vector_type(8)));
typedef unsigned int u32x4_t __attribute__((ext_vector_type(4)));

__device__ __forceinline__ unsigned short f2bf(float x) {
  unsigned int u = __builtin_bit_cast(unsigned int, x);
  u += 0x7FFFu + ((u >> 16) & 1u);  // RNE
  return (unsigned short)(u >> 16);
}

__device__ __forceinline__ unsigned int cvtpk(float lo, float hi) {
  unsigned int r;
  asm("v_cvt_pk_bf16_f32 %0, %1, %2" : "=v"(r) : "v"(lo), "v"(hi));
  return r;
}

__device__ __forceinline__ void gload_lds16(const void* g, void* l) {
  __builtin_amdgcn_global_load_lds(
      (const __attribute__((address_space(1))) uint32_t*)g,
      (__attribute__((address_space(3))) uint32_t*)l, 16, 0, 0);
}

// ---------------- kernel 0: c1/c2[k] = sum_f W[f][k]*a{1,2}[f] ----------------
__global__ void gat_cvec(const float* __restrict__ W, const float* __restrict__ a,
                         float* __restrict__ c1, float* __restrict__ c2) {
  const int k = threadIdx.x;
  float acc1 = 0.f, acc2 = 0.f;
#pragma unroll 8
  for (int f = 0; f < FD; ++f) {
    float w = W[f * FD + k];
    acc1 = fmaf(w, a[f], acc1);
    acc2 = fmaf(w, a[FD + f], acc2);
  }
  c1[k] = acc1;
  c2[k] = acc2;
}

// ---- fused prep: blocks [0,512) wht | [512,2560) pack | [2560,4608) svec ----
// whTK[ktile(64k)][f(256)][k%64] with the G4 XOR swizzle PRE-APPLIED:
// idx = ktile*16384 + f*64 + ((k>>3)^(f&7))*8 + (k&7).   (rule #21)
__launch_bounds__(256)
__global__ void gat_prep(const float* __restrict__ h, const float* __restrict__ W,
                         const int* __restrict__ adj, const float* __restrict__ c1,
                         const float* __restrict__ c2,
                         unsigned short* __restrict__ whTK,
                         unsigned long long* __restrict__ mask64,
                         float* __restrict__ s1, float* __restrict__ s2) {
  __shared__ __align__(16) float hT[64][64];
  __shared__ __align__(16) float wT[64][64];
  const int b = blockIdx.x;
  const int t = threadIdx.x;

  if (b < 512) {
    const int i0 = (b & 127) * 64;  // k-range (rows of Wh)
    const int f0 = (b >> 7) * 64;
    const int r = t & 63;
    const int kq = t >> 6;
    const int ty = t >> 4;
    const int tx = t & 15;
    float acc[4][4] = {};
    for (int k0 = 0; k0 < FD; k0 += 64) {
#pragma unroll
      for (int kk = 0; kk < 16; kk += 4) {
        float4 v = *(const float4*)(h + (size_t)(i0 + r) * FD + k0 + kq * 16 + kk);
        hT[kq * 16 + kk + 0][r] = v.x;
        hT[kq * 16 + kk + 1][r] = v.y;
        hT[kq * 16 + kk + 2][r] = v.z;
        hT[kq * 16 + kk + 3][r] = v.w;
        float4 u = *(const float4*)(W + (size_t)(f0 + r) * FD + k0 + kq * 16 + kk);
        wT[kq * 16 + kk + 0][r] = u.x;
        wT[kq * 16 + kk + 1][r] = u.y;
        wT[kq * 16 + kk + 2][r] = u.z;
        wT[kq * 16 + kk + 3][r] = u.w;
      }
      __syncthreads();
#pragma unroll 8
      for (int kk = 0; kk < 64; ++kk) {
        float4 av = *(const float4*)&hT[kk][ty * 4];
        float4 bv = *(const float4*)&wT[kk][tx * 4];
        acc[0][0] = fmaf(av.x, bv.x, acc[0][0]);
        acc[0][1] = fmaf(av.x, bv.y, acc[0][1]);
        acc[0][2] = fmaf(av.x, bv.z, acc[0][2]);
        acc[0][3] = fmaf(av.x, bv.w, acc[0][3]);
        acc[1][0] = fmaf(av.y, bv.x, acc[1][0]);
        acc[1][1] = fmaf(av.y, bv.y, acc[1][1]);
        acc[1][2] = fmaf(av.y, bv.z, acc[1][2]);
        acc[1][3] = fmaf(av.y, bv.w, acc[1][3]);
        acc[2][0] = fmaf(av.z, bv.x, acc[2][0]);
        acc[2][1] = fmaf(av.z, bv.y, acc[2][1]);
        acc[2][2] = fmaf(av.z, bv.z, acc[2][2]);
        acc[2][3] = fmaf(av.z, bv.w, acc[2][3]);
        acc[3][0] = fmaf(av.w, bv.x, acc[3][0]);
        acc[3][1] = fmaf(av.w, bv.y, acc[3][1]);
        acc[3][2] = fmaf(av.w, bv.z, acc[3][2]);
        acc[3][3] = fmaf(av.w, bv.w, acc[3][3]);
      }
      __syncthreads();
    }
    const int iv = i0 + ty * 4;
    const int ktile = iv >> 6;
    const int kl = iv & 63;
#pragma unroll
    for (int j = 0; j < 4; ++j) {
      const int f = f0 + tx * 4 + j;
      ushort4 o;
      o.x = f2bf(acc[0][j]);
      o.y = f2bf(acc[1][j]);
      o.z = f2bf(acc[2][j]);
      o.w = f2bf(acc[3][j]);
      const size_t idx = (size_t)ktile * 16384 + (size_t)f * 64 +
                         (size_t)(((kl >> 3) ^ (f & 7)) * 8 + (kl & 7));
      *(ushort4*)(whTK + idx) = o;
    }
  } else if (b < 2560) {
    const int vb = b - 512;
    const int lane = t & 63;
    const int w = t >> 6;
    const size_t ngroups = (size_t)NN * NN / 256;
    const size_t nw = (size_t)2048 * 4;
    for (size_t g = (size_t)vb * 4 + w; g < ngroups; g += nw) {
      const int* p = adj + g * 256 + lane;
      int v0 = p[0];
      int v1 = p[64];
      int v2 = p[128];
      int v3 = p[192];
      unsigned long long m0 = __ballot(v0 != 0);
      unsigned long long m1 = __ballot(v1 != 0);
      unsigned long long m2 = __ballot(v2 != 0);
      unsigned long long m3 = __ballot(v3 != 0);
      if (lane < 4) {
        unsigned long long mv = lane == 0 ? m0 : lane == 1 ? m1 : lane == 2 ? m2 : m3;
        mask64[g * 4 + lane] = mv;
      }
    }
  } else {
    const int i = (b - 2560) * 4 + (t >> 6);
    const int lane = t & 63;
    float4 hv = *(const float4*)(h + (size_t)i * FD + lane * 4);
    float4 u = *(const float4*)(c1 + lane * 4);
    float4 v = *(const float4*)(c2 + lane * 4);
    float d1 = hv.x * u.x + hv.y * u.y + hv.z * u.z + hv.w * u.w;
    float d2 = hv.x * v.x + hv.y * v.y + hv.z * v.z + hv.w * v.w;
#pragma unroll
    for (int m = 1; m < 64; m <<= 1) {
      d1 += __shfl_xor(d1, m, 64);
      d2 += __shfl_xor(d2, m, 64);
    }
    if (lane == 0) {
      s1[i] = d1 * LOG2E;
      s2[i] = d2 * LOG2E;
    }
  }
}

// ------------- attention: m97-structure, 36 KB LDS -> 4 blocks/CU, no tail ---
// grid 1024 = 64 rs x 2 fh x 8 kq; block 256 thr = 4 waves; 128 rows x 128 f
// x 1024 k; 16 iters of BK=64. Single-buffered B (syncthreads drains vmcnt(0)
// anyway, dbuf bought nothing). exp2 via __builtin_amdgcn_exp2f (1 instr, not
// OCML). Mask word loaded at iter-top (hides under P-VALU).
__launch_bounds__(256, 4)
__global__ void gat_attn(const unsigned int* __restrict__ maskp,
                         const float* __restrict__ s1g, const float* __restrict__ s2g,
                         const unsigned short* __restrict__ whTK,
                         float* __restrict__ accP, float* __restrict__ lP) {
  __shared__ __align__(16) unsigned short Bs[64 * 128];  // [f][k] swz, 16 KB
  __shared__ __align__(16) unsigned short As[128 * 64];  // [row][k] swz, 16 KB
  __shared__ __align__(16) float s2s[1024];              // 4 KB; reused as lred

  const int tid = threadIdx.x;
  const int lane = tid & 63;
  const int w = tid >> 6;
  const int kq = blockIdx.x & 7;
  const int fh = (blockIdx.x >> 3) & 1;
  const int rs = blockIdx.x >> 4;
  const int kbase = kq * 1024;

  // P-phase role
  const int tr = tid & 127;
  const int kh = tid >> 7;
  const float s1r = s1g[rs * 128 + tr];
  const unsigned int* mrow =
      maskp + (size_t)(rs * 128 + tr) * (NN / 32) + (kbase >> 5) + kh;

  // MFMA-phase role
  const int wr = w & 1;
  const int wc = w >> 1;
  const int r16 = lane & 15;
  const int kg = lane >> 4;

  // stage s2 tile (whole block k-range)
  *(float4*)&s2s[tid * 4] = *(const float4*)(s2g + kbase + tid * 4);

  unsigned int mw = mrow[0];
  float l_acc = 0.f;

  f32x4_t acc[4][4];
  const f32x4_t zero4 = {0.f, 0.f, 0.f, 0.f};
#pragma unroll
  for (int rt = 0; rt < 4; ++rt)
#pragma unroll
    for (int ct = 0; ct < 4; ++ct) acc[rt][ct] = zero4;

  __syncthreads();  // s2s ready

  for (int it = 0; it < 16; ++it) {
    // ---- stage B(it) (completes at barrier-1's vmcnt(0)) ----
    {
      const char* bsrc = (const char*)whTK + (size_t)(kq * 16 + it) * 32768 + fh * 16384;
      char* bdst = (char*)Bs;
#pragma unroll
      for (int q = 0; q < 4; ++q)
        gload_lds16(bsrc + w * 4096 + q * 1024 + lane * 16, bdst + w * 4096 + q * 1024);
    }
    // next iter's mask word: issued early, hides under P-VALU
    unsigned int mwn = (it + 1 < 16) ? mrow[(it + 1) * 2] : 0u;

    // ---- P-phase: 32 entries (1 row x 32 k), ds_write into swizzled A ----
    {
      const int kloc = it * 64 + kh * 32;
#pragma unroll
      for (int c = 0; c < 4; ++c) {
        float4 sa = *(const float4*)&s2s[kloc + c * 8];      // broadcast
        float4 sb = *(const float4*)&s2s[kloc + c * 8 + 4];  // broadcast
        const float sv[8] = {sa.x, sa.y, sa.z, sa.w, sb.x, sb.y, sb.z, sb.w};
        float p[8];
#pragma unroll
        for (int e = 0; e < 8; ++e) {
          float x = s1r + sv[e];
          x = fmaxf(x, SLOPE * x);
          float pv = __builtin_amdgcn_exp2f(x);  // v_exp_f32, 1 instr
          p[e] = ((mw >> (c * 8 + e)) & 1u) ? pv : 0.f;
        }
        l_acc += ((p[0] + p[1]) + (p[2] + p[3])) + ((p[4] + p[5]) + (p[6] + p[7]));
        u32x4_t wv;
        wv[0] = cvtpk(p[0], p[1]);
        wv[1] = cvtpk(p[2], p[3]);
        wv[2] = cvtpk(p[4], p[5]);
        wv[3] = cvtpk(p[6], p[7]);
        const int chunk = (kh * 4 + c) ^ (tr & 7);
        *(u32x4_t*)((char*)As + tr * 128 + chunk * 16) = wv;  // ds_write_b128
      }
    }

    __syncthreads();  // A(it) written, B(it) staged (vmcnt(0) drain)

    // ---- MFMA phase: frags from LDS, 32 MFMA ----
    {
#pragma unroll
      for (int kc = 0; kc < 2; ++kc) {
        bf16x8_t a0, a1, a2, a3, b0, b1, b2, b3;
        {
          const int row0 = wr * 64 + r16;
          const int ch = kc * 4 + kg;
          a0 = *(const bf16x8_t*)((const char*)As + (row0 + 0) * 128 + ((ch ^ ((row0 + 0) & 7)) * 16));
          a1 = *(const bf16x8_t*)((const char*)As + (row0 + 16) * 128 + ((ch ^ ((row0 + 16) & 7)) * 16));
          a2 = *(const bf16x8_t*)((const char*)As + (row0 + 32) * 128 + ((ch ^ ((row0 + 32) & 7)) * 16));
          a3 = *(const bf16x8_t*)((const char*)As + (row0 + 48) * 128 + ((ch ^ ((row0 + 48) & 7)) * 16));
          const int f0l = wc * 64 + r16;
          b0 = *(const bf16x8_t*)((const char*)Bs + (f0l + 0) * 128 + ((ch ^ ((f0l + 0) & 7)) * 16));
          b1 = *(const bf16x8_t*)((const char*)Bs + (f0l + 16) * 128 + ((ch ^ ((f0l + 16) & 7)) * 16));
          b2 = *(const bf16x8_t*)((const char*)Bs + (f0l + 32) * 128 + ((ch ^ ((f0l + 32) & 7)) * 16));
          b3 = *(const bf16x8_t*)((const char*)Bs + (f0l + 48) * 128 + ((ch ^ ((f0l + 48) & 7)) * 16));
        }
        acc[0][0] = __builtin_amdgcn_mfma_f32_16x16x32_bf16(a0, b0, acc[0][0], 0, 0, 0);
        acc[0][1] = __builtin_amdgcn_mfma_f32_16x16x32_bf16(a0, b1, acc[0][1], 0, 0, 0);
        acc[0][2] = __builtin_amdgcn_mfma_f32_16x16x32_bf16(a0, b2, acc[0][2], 0, 0, 0);
        acc[0][3] = __builtin_amdgcn_mfma_f32_16x16x32_bf16(a0, b3, acc[0][3], 0, 0, 0);
        acc[1][0] = __builtin_amdgcn_mfma_f32_16x16x32_bf16(a1, b0, acc[1][0], 0, 0, 0);
        acc[1][1] = __builtin_amdgcn_mfma_f32_16x16x32_bf16(a1, b1, acc[1][1], 0, 0, 0);
        acc[1][2] = __builtin_amdgcn_mfma_f32_16x16x32_bf16(a1, b2, acc[1][2], 0, 0, 0);
        acc[1][3] = __builtin_amdgcn_mfma_f32_16x16x32_bf16(a1, b3, acc[1][3], 0, 0, 0);
        acc[2][0] = __builtin_amdgcn_mfma_f32_16x16x32_bf16(a2, b0, acc[2][0], 0, 0, 0);
        acc[2][1] = __builtin_amdgcn_mfma_f32_16x16x32_bf16(a2, b1, acc[2][1], 0, 0, 0);
        acc[2][2] = __builtin_amdgcn_mfma_f32_16x16x32_bf16(a2, b2, acc[2][2], 0, 0, 0);
        acc[2][3] = __builtin_amdgcn_mfma_f32_16x16x32_bf16(a2, b3, acc[2][3], 0, 0, 0);
        acc[3][0] = __builtin_amdgcn_mfma_f32_16x16x32_bf16(a3, b0, acc[3][0], 0, 0, 0);
        acc[3][1] = __builtin_amdgcn_mfma_f32_16x16x32_bf16(a3, b1, acc[3][1], 0, 0, 0);
        acc[3][2] = __builtin_amdgcn_mfma_f32_16x16x32_bf16(a3, b2, acc[3][2], 0, 0, 0);
        acc[3][3] = __builtin_amdgcn_mfma_f32_16x16x32_bf16(a3, b3, acc[3][3], 0, 0, 0);
      }
    }
    __syncthreads();  // tiles consumed; safe to rewrite next iter
    mw = mwn;
  }

  // ---- l partials (s2s reused as lred[2][128]) ----
  float* lred = s2s;
  lred[kh * 128 + tr] = l_acc;
  __syncthreads();
  if (tid < 128)
    lP[(size_t)kq * NN + rs * 128 + tid] = lred[tid] + lred[128 + tid];

  // ---- acc partials ----
  float* ap = accP + (size_t)kq * NN * FD;
#pragma unroll
  for (int rt = 0; rt < 4; ++rt) {
#pragma unroll
    for (int ct = 0; ct < 4; ++ct) {
      const int col = fh * 128 + wc * 64 + ct * 16 + r16;
#pragma unroll
      for (int g = 0; g < 4; ++g) {
        const int row = rs * 128 + wr * 64 + rt * 16 + kg * 4 + g;
        ap[(size_t)row * FD + col] = acc[rt][ct][g];
      }
    }
  }
}

// ---------------- merge: out[i][f] = sum_kq accP / sum_kq lP -----------------
__global__ void gat_merge(const float* __restrict__ accP, const float* __restrict__ lP,
                          float* __restrict__ out) {
  const int i = blockIdx.x;
  const int f = threadIdx.x;
  float s = 0.f, l = 0.f;
#pragma unroll
  for (int q = 0; q < 8; ++q) {
    s += accP[((size_t)q * NN + i) * FD + f];
    l += lP[(size_t)q * NN + i];
  }
  out[(size_t)i * FD + f] = s / l;
}

extern "C" void kernel_launch(void* const* d_in, const int* in_sizes, int n_in,
                              void* d_out, int out_size, void* d_ws, size_t ws_size,
                              hipStream_t stream) {
  const float* h = (const float*)d_in[0];
  const int* adj = (const int*)d_in[1];
  const float* W = (const float*)d_in[2];
  const float* a = (const float*)d_in[3];
  float* out = (float*)d_out;

  char* ws = (char*)d_ws;
  unsigned short* whTK = (unsigned short*)ws;                        // 4 MB
  float* s1 = (float*)(ws + 4194304);                                // 32 KB
  float* s2 = (float*)(ws + 4194304 + 32768);                        // 32 KB
  float* c1 = (float*)(ws + 4194304 + 65536);                        // 1 KB
  float* c2 = (float*)(ws + 4194304 + 65536 + 1024);                 // 1 KB
  unsigned long long* mask64 = (unsigned long long*)(ws + 5242880);  // 8 MB
  float* accP = (float*)(ws + 16777216);                             // 8 x 8 MB
  float* lP = (float*)(ws + 16777216 + 8ull * NN * FD * 4);          // 256 KB

  gat_cvec<<<1, 256, 0, stream>>>(W, a, c1, c2);
  gat_prep<<<4608, 256, 0, stream>>>(h, W, adj, c1, c2, whTK, mask64, s1, s2);
  gat_attn<<<1024, 256, 0, stream>>>((const unsigned int*)mask64, s1, s2, whTK, accP, lP);
  gat_merge<<<NN, FD, 0, stream>>>(accP, lP, out);
}

// Round 16
// 159.193 us; speedup vs baseline: 2.2294x; 1.0596x over previous
//
#include <hip/hip_runtime.h>
#include <hip/hip_bf16.h>
#include <stdint.h>

#define NN 8192
#define FD 256
#define SLOPE 0.2f
#define LOG2E 1.44269504088896f

typedef float f32x4_t __attribute__((ext_vector_type(4)));
typedef __bf16 bf16x8_t __attribute__((ext_vector_type(8)));
typedef unsigned int u32x4_t __attribute__((ext_vector_type(4)));

__device__ __forceinline__ unsigned short f2bf(float x) {
  unsigned int u = __builtin_bit_cast(unsigned int, x);
  u += 0x7FFFu + ((u >> 16) & 1u);  // RNE
  return (unsigned short)(u >> 16);
}

__device__ __forceinline__ unsigned int cvtpk(float lo, float hi) {
  unsigned int r;
  asm("v_cvt_pk_bf16_f32 %0, %1, %2" : "=v"(r) : "v"(lo), "v"(hi));
  return r;
}

__device__ __forceinline__ void gload_lds16(const void* g, void* l) {
  __builtin_amdgcn_global_load_lds(
      (const __attribute__((address_space(1))) uint32_t*)g,
      (__attribute__((address_space(3))) uint32_t*)l, 16, 0, 0);
}

// ---------------- kernel 0: c1/c2[k] = sum_f W[f][k]*a{1,2}[f] ----------------
__global__ void gat_cvec(const float* __restrict__ W, const float* __restrict__ a,
                         float* __restrict__ c1, float* __restrict__ c2) {
  const int k = threadIdx.x;
  float acc1 = 0.f, acc2 = 0.f;
#pragma unroll 8
  for (int f = 0; f < FD; ++f) {
    float w = W[f * FD + k];
    acc1 = fmaf(w, a[f], acc1);
    acc2 = fmaf(w, a[FD + f], acc2);
  }
  c1[k] = acc1;
  c2[k] = acc2;
}

// ---- fused prep: blocks [0,512) wht | [512,2560) pack | [2560,4608) svec ----
// whTK[ktile(64k)][f(256)][k%64] with the G4 XOR swizzle PRE-APPLIED:
// idx = ktile*16384 + f*64 + ((k>>3)^(f&7))*8 + (k&7).   (rule #21)
__launch_bounds__(256)
__global__ void gat_prep(const float* __restrict__ h, const float* __restrict__ W,
                         const int* __restrict__ adj, const float* __restrict__ c1,
                         const float* __restrict__ c2,
                         unsigned short* __restrict__ whTK,
                         unsigned long long* __restrict__ mask64,
                         float* __restrict__ s1, float* __restrict__ s2) {
  __shared__ __align__(16) float hT[64][64];
  __shared__ __align__(16) float wT[64][64];
  const int b = blockIdx.x;
  const int t = threadIdx.x;

  if (b < 512) {
    const int i0 = (b & 127) * 64;  // k-range (rows of Wh)
    const int f0 = (b >> 7) * 64;
    const int r = t & 63;
    const int kq = t >> 6;
    const int ty = t >> 4;
    const int tx = t & 15;
    float acc[4][4] = {};
    for (int k0 = 0; k0 < FD; k0 += 64) {
#pragma unroll
      for (int kk = 0; kk < 16; kk += 4) {
        float4 v = *(const float4*)(h + (size_t)(i0 + r) * FD + k0 + kq * 16 + kk);
        hT[kq * 16 + kk + 0][r] = v.x;
        hT[kq * 16 + kk + 1][r] = v.y;
        hT[kq * 16 + kk + 2][r] = v.z;
        hT[kq * 16 + kk + 3][r] = v.w;
        float4 u = *(const float4*)(W + (size_t)(f0 + r) * FD + k0 + kq * 16 + kk);
        wT[kq * 16 + kk + 0][r] = u.x;
        wT[kq * 16 + kk + 1][r] = u.y;
        wT[kq * 16 + kk + 2][r] = u.z;
        wT[kq * 16 + kk + 3][r] = u.w;
      }
      __syncthreads();
#pragma unroll 8
      for (int kk = 0; kk < 64; ++kk) {
        float4 av = *(const float4*)&hT[kk][ty * 4];
        float4 bv = *(const float4*)&wT[kk][tx * 4];
        acc[0][0] = fmaf(av.x, bv.x, acc[0][0]);
        acc[0][1] = fmaf(av.x, bv.y, acc[0][1]);
        acc[0][2] = fmaf(av.x, bv.z, acc[0][2]);
        acc[0][3] = fmaf(av.x, bv.w, acc[0][3]);
        acc[1][0] = fmaf(av.y, bv.x, acc[1][0]);
        acc[1][1] = fmaf(av.y, bv.y, acc[1][1]);
        acc[1][2] = fmaf(av.y, bv.z, acc[1][2]);
        acc[1][3] = fmaf(av.y, bv.w, acc[1][3]);
        acc[2][0] = fmaf(av.z, bv.x, acc[2][0]);
        acc[2][1] = fmaf(av.z, bv.y, acc[2][1]);
        acc[2][2] = fmaf(av.z, bv.z, acc[2][2]);
        acc[2][3] = fmaf(av.z, bv.w, acc[2][3]);
        acc[3][0] = fmaf(av.w, bv.x, acc[3][0]);
        acc[3][1] = fmaf(av.w, bv.y, acc[3][1]);
        acc[3][2] = fmaf(av.w, bv.z, acc[3][2]);
        acc[3][3] = fmaf(av.w, bv.w, acc[3][3]);
      }
      __syncthreads();
    }
    const int iv = i0 + ty * 4;
    const int ktile = iv >> 6;
    const int kl = iv & 63;
#pragma unroll
    for (int j = 0; j < 4; ++j) {
      const int f = f0 + tx * 4 + j;
      ushort4 o;
      o.x = f2bf(acc[0][j]);
      o.y = f2bf(acc[1][j]);
      o.z = f2bf(acc[2][j]);
      o.w = f2bf(acc[3][j]);
      const size_t idx = (size_t)ktile * 16384 + (size_t)f * 64 +
                         (size_t)(((kl >> 3) ^ (f & 7)) * 8 + (kl & 7));
      *(ushort4*)(whTK + idx) = o;
    }
  } else if (b < 2560) {
    const int vb = b - 512;
    const int lane = t & 63;
    const int w = t >> 6;
    const size_t ngroups = (size_t)NN * NN / 256;
    const size_t nw = (size_t)2048 * 4;
    for (size_t g = (size_t)vb * 4 + w; g < ngroups; g += nw) {
      const int* p = adj + g * 256 + lane;
      int v0 = p[0];
      int v1 = p[64];
      int v2 = p[128];
      int v3 = p[192];
      unsigned long long m0 = __ballot(v0 != 0);
      unsigned long long m1 = __ballot(v1 != 0);
      unsigned long long m2 = __ballot(v2 != 0);
      unsigned long long m3 = __ballot(v3 != 0);
      if (lane < 4) {
        unsigned long long mv = lane == 0 ? m0 : lane == 1 ? m1 : lane == 2 ? m2 : m3;
        mask64[g * 4 + lane] = mv;
      }
    }
  } else {
    const int i = (b - 2560) * 4 + (t >> 6);
    const int lane = t & 63;
    float4 hv = *(const float4*)(h + (size_t)i * FD + lane * 4);
    float4 u = *(const float4*)(c1 + lane * 4);
    float4 v = *(const float4*)(c2 + lane * 4);
    float d1 = hv.x * u.x + hv.y * u.y + hv.z * u.z + hv.w * u.w;
    float d2 = hv.x * v.x + hv.y * v.y + hv.z * v.z + hv.w * v.w;
#pragma unroll
    for (int m = 1; m < 64; m <<= 1) {
      d1 += __shfl_xor(d1, m, 64);
      d2 += __shfl_xor(d2, m, 64);
    }
    if (lane == 0) {
      s1[i] = d1 * LOG2E;
      s2[i] = d2 * LOG2E;
    }
  }
}

// ---- attention: 128 rows x FULL 256 f per block (no fh split), m97-style ----
// grid 512 = 64 rs x 8 kq (kq = bx&7 -> XCD-local B+mask); block 256 thr =
// 4 waves; 16 iters of BK=64 over a 1024-k slice. Per iter: [stage full 32 KB
// B tile via 8 gload_lds/wave] [P-VALU once (no fh duplication): 1 row x 32 k
// per thread -> swizzled A] barrier [ds_read frags + 64 MFMA/wave] barrier.
// LDS = 32 KB B + 16 KB A + 4 KB s2 = 52 KB -> 2 blocks/CU; VGPR cap 256.
__launch_bounds__(256, 2)
__global__ void gat_attn(const unsigned int* __restrict__ maskp,
                         const float* __restrict__ s1g, const float* __restrict__ s2g,
                         const unsigned short* __restrict__ whTK,
                         float* __restrict__ accP, float* __restrict__ lP) {
  __shared__ __align__(16) unsigned short Bs[64 * 256];  // [f][k] swz, 32 KB
  __shared__ __align__(16) unsigned short As[128 * 64];  // [row][k] swz, 16 KB
  __shared__ __align__(16) float s2s[1024];              // 4 KB; reused as lred

  const int tid = threadIdx.x;
  const int lane = tid & 63;
  const int w = tid >> 6;
  const int kq = blockIdx.x & 7;
  const int rs = blockIdx.x >> 3;
  const int kbase = kq * 1024;

  // P-phase role
  const int tr = tid & 127;
  const int kh = tid >> 7;
  const float s1r = s1g[rs * 128 + tr];
  const unsigned int* mrow =
      maskp + (size_t)(rs * 128 + tr) * (NN / 32) + (kbase >> 5) + kh;

  // MFMA-phase role: wave w -> rows (w&1)*64, cols (w>>1)*128
  const int wr = w & 1;
  const int wc = w >> 1;
  const int r16 = lane & 15;
  const int kg = lane >> 6 ? 0 : lane >> 4;  // kg = lane>>4 (0..3)

  // stage s2 tile (whole block k-range)
  *(float4*)&s2s[tid * 4] = *(const float4*)(s2g + kbase + tid * 4);

  unsigned int mw = mrow[0];
  float l_acc = 0.f;

  f32x4_t acc[4][8];
  const f32x4_t zero4 = {0.f, 0.f, 0.f, 0.f};
#pragma unroll
  for (int rt = 0; rt < 4; ++rt)
#pragma unroll
    for (int ct = 0; ct < 8; ++ct) acc[rt][ct] = zero4;

  __syncthreads();  // s2s ready

  for (int it = 0; it < 16; ++it) {
    // ---- stage B(it): full 256-f tile, 32 KB (completes at barrier vmcnt(0))
    {
      const char* bsrc = (const char*)whTK + (size_t)(kq * 16 + it) * 32768;
      char* bdst = (char*)Bs;
#pragma unroll
      for (int q = 0; q < 8; ++q)
        gload_lds16(bsrc + w * 8192 + q * 1024 + lane * 16, bdst + w * 8192 + q * 1024);
    }
    // next iter's mask word: issued early, hides under P-VALU
    unsigned int mwn = (it + 1 < 16) ? mrow[(it + 1) * 2] : 0u;

    // ---- P-phase: 32 entries (1 row x 32 k), ds_write into swizzled A ----
    {
      const int kloc = it * 64 + kh * 32;
#pragma unroll
      for (int c = 0; c < 4; ++c) {
        float4 sa = *(const float4*)&s2s[kloc + c * 8];      // broadcast
        float4 sb = *(const float4*)&s2s[kloc + c * 8 + 4];  // broadcast
        const float sv[8] = {sa.x, sa.y, sa.z, sa.w, sb.x, sb.y, sb.z, sb.w};
        float p[8];
#pragma unroll
        for (int e = 0; e < 8; ++e) {
          float x = s1r + sv[e];
          x = fmaxf(x, SLOPE * x);
          float pv = __builtin_amdgcn_exp2f(x);  // v_exp_f32
          p[e] = ((mw >> (c * 8 + e)) & 1u) ? pv : 0.f;
        }
        l_acc += ((p[0] + p[1]) + (p[2] + p[3])) + ((p[4] + p[5]) + (p[6] + p[7]));
        u32x4_t wv;
        wv[0] = cvtpk(p[0], p[1]);
        wv[1] = cvtpk(p[2], p[3]);
        wv[2] = cvtpk(p[4], p[5]);
        wv[3] = cvtpk(p[6], p[7]);
        const int chunk = (kh * 4 + c) ^ (tr & 7);
        *(u32x4_t*)((char*)As + tr * 128 + chunk * 16) = wv;  // ds_write_b128
      }
    }

    __syncthreads();  // A(it) written, B(it) staged (vmcnt(0) drain)

    // ---- MFMA phase: frags from LDS, 64 MFMA/wave ----
    {
#pragma unroll
      for (int kc = 0; kc < 2; ++kc) {
        const int ch = kc * 4 + kg;
        bf16x8_t a0, a1, a2, a3;
        {
          const int row0 = wr * 64 + r16;
          a0 = *(const bf16x8_t*)((const char*)As + (row0 + 0) * 128 + ((ch ^ ((row0 + 0) & 7)) * 16));
          a1 = *(const bf16x8_t*)((const char*)As + (row0 + 16) * 128 + ((ch ^ ((row0 + 16) & 7)) * 16));
          a2 = *(const bf16x8_t*)((const char*)As + (row0 + 32) * 128 + ((ch ^ ((row0 + 32) & 7)) * 16));
          a3 = *(const bf16x8_t*)((const char*)As + (row0 + 48) * 128 + ((ch ^ ((row0 + 48) & 7)) * 16));
        }
#pragma unroll
        for (int cp = 0; cp < 2; ++cp) {  // two 4-col groups of 4 B-frags
          bf16x8_t b0, b1, b2, b3;
          {
            const int f0l = wc * 128 + cp * 64 + r16;
            b0 = *(const bf16x8_t*)((const char*)Bs + (f0l + 0) * 128 + ((ch ^ ((f0l + 0) & 7)) * 16));
            b1 = *(const bf16x8_t*)((const char*)Bs + (f0l + 16) * 128 + ((ch ^ ((f0l + 16) & 7)) * 16));
            b2 = *(const bf16x8_t*)((const char*)Bs + (f0l + 32) * 128 + ((ch ^ ((f0l + 32) & 7)) * 16));
            b3 = *(const bf16x8_t*)((const char*)Bs + (f0l + 48) * 128 + ((ch ^ ((f0l + 48) & 7)) * 16));
          }
          const int c0 = cp * 4;
          acc[0][c0 + 0] = __builtin_amdgcn_mfma_f32_16x16x32_bf16(a0, b0, acc[0][c0 + 0], 0, 0, 0);
          acc[0][c0 + 1] = __builtin_amdgcn_mfma_f32_16x16x32_bf16(a0, b1, acc[0][c0 + 1], 0, 0, 0);
          acc[0][c0 + 2] = __builtin_amdgcn_mfma_f32_16x16x32_bf16(a0, b2, acc[0][c0 + 2], 0, 0, 0);
          acc[0][c0 + 3] = __builtin_amdgcn_mfma_f32_16x16x32_bf16(a0, b3, acc[0][c0 + 3], 0, 0, 0);
          acc[1][c0 + 0] = __builtin_amdgcn_mfma_f32_16x16x32_bf16(a1, b0, acc[1][c0 + 0], 0, 0, 0);
          acc[1][c0 + 1] = __builtin_amdgcn_mfma_f32_16x16x32_bf16(a1, b1, acc[1][c0 + 1], 0, 0, 0);
          acc[1][c0 + 2] = __builtin_amdgcn_mfma_f32_16x16x32_bf16(a1, b2, acc[1][c0 + 2], 0, 0, 0);
          acc[1][c0 + 3] = __builtin_amdgcn_mfma_f32_16x16x32_bf16(a1, b3, acc[1][c0 + 3], 0, 0, 0);
          acc[2][c0 + 0] = __builtin_amdgcn_mfma_f32_16x16x32_bf16(a2, b0, acc[2][c0 + 0], 0, 0, 0);
          acc[2][c0 + 1] = __builtin_amdgcn_mfma_f32_16x16x32_bf16(a2, b1, acc[2][c0 + 1], 0, 0, 0);
          acc[2][c0 + 2] = __builtin_amdgcn_mfma_f32_16x16x32_bf16(a2, b2, acc[2][c0 + 2], 0, 0, 0);
          acc[2][c0 + 3] = __builtin_amdgcn_mfma_f32_16x16x32_bf16(a2, b3, acc[2][c0 + 3], 0, 0, 0);
          acc[3][c0 + 0] = __builtin_amdgcn_mfma_f32_16x16x32_bf16(a3, b0, acc[3][c0 + 0], 0, 0, 0);
          acc[3][c0 + 1] = __builtin_amdgcn_mfma_f32_16x16x32_bf16(a3, b1, acc[3][c0 + 1], 0, 0, 0);
          acc[3][c0 + 2] = __builtin_amdgcn_mfma_f32_16x16x32_bf16(a3, b2, acc[3][c0 + 2], 0, 0, 0);
          acc[3][c0 + 3] = __builtin_amdgcn_mfma_f32_16x16x32_bf16(a3, b3, acc[3][c0 + 3], 0, 0, 0);
        }
      }
    }
    __syncthreads();  // tiles consumed; safe to rewrite next iter
    mw = mwn;
  }

  // ---- l partials (s2s reused as lred[2][128]) ----
  float* lred = s2s;
  lred[kh * 128 + tr] = l_acc;
  __syncthreads();
  if (tid < 128)
    lP[(size_t)kq * NN + rs * 128 + tid] = lred[tid] + lred[128 + tid];

  // ---- acc partials ----
  float* ap = accP + (size_t)kq * NN * FD;
#pragma unroll
  for (int rt = 0; rt < 4; ++rt) {
#pragma unroll
    for (int ct = 0; ct < 8; ++ct) {
      const int col = wc * 128 + ct * 16 + r16;
#pragma unroll
      for (int g = 0; g < 4; ++g) {
        const int row = rs * 128 + wr * 64 + rt * 16 + kg * 4 + g;
        ap[(size_t)row * FD + col] = acc[rt][ct][g];
      }
    }
  }
}

// ---------------- merge: out[i][f] = sum_kq accP / sum_kq lP -----------------
__global__ void gat_merge(const float* __restrict__ accP, const float* __restrict__ lP,
                          float* __restrict__ out) {
  const int i = blockIdx.x;
  const int f = threadIdx.x;
  float s = 0.f, l = 0.f;
#pragma unroll
  for (int q = 0; q < 8; ++q) {
    s += accP[((size_t)q * NN + i) * FD + f];
    l += lP[(size_t)q * NN + i];
  }
  out[(size_t)i * FD + f] = s / l;
}

extern "C" void kernel_launch(void* const* d_in, const int* in_sizes, int n_in,
                              void* d_out, int out_size, void* d_ws, size_t ws_size,
                              hipStream_t stream) {
  const float* h = (const float*)d_in[0];
  const int* adj = (const int*)d_in[1];
  const float* W = (const float*)d_in[2];
  const float* a = (const float*)d_in[3];
  float* out = (float*)d_out;

  char* ws = (char*)d_ws;
  unsigned short* whTK = (unsigned short*)ws;                        // 4 MB
  float* s1 = (float*)(ws + 4194304);                                // 32 KB
  float* s2 = (float*)(ws + 4194304 + 32768);                        // 32 KB
  float* c1 = (float*)(ws + 4194304 + 65536);                        // 1 KB
  float* c2 = (float*)(ws + 4194304 + 65536 + 1024);                 // 1 KB
  unsigned long long* mask64 = (unsigned long long*)(ws + 5242880);  // 8 MB
  float* accP = (float*)(ws + 16777216);                             // 8 x 8 MB
  float* lP = (float*)(ws + 16777216 + 8ull * NN * FD * 4);          // 256 KB

  gat_cvec<<<1, 256, 0, stream>>>(W, a, c1, c2);
  gat_prep<<<4608, 256, 0, stream>>>(h, W, adj, c1, c2, whTK, mask64, s1, s2);
  gat_attn<<<512, 256, 0, stream>>>((const unsigned int*)mask64, s1, s2, whTK, accP, lP);
  gat_merge<<<NN, FD, 0, stream>>>(accP, lP, out);
}

// Round 17
// 133.705 us; speedup vs baseline: 2.6543x; 1.1906x over previous
//
#include <hip/hip_runtime.h>
#include <hip/hip_bf16.h>
#include <stdint.h>

#define NN 8192
#define FD 256
#define SLOPE 0.2f
#define LOG2E 1.44269504088896f

typedef float f32x4_t __attribute__((ext_vector_type(4)));
typedef __bf16 bf16x8_t __attribute__((ext_vector_type(8)));
typedef unsigned int u32x2_t __attribute__((ext_vector_type(2)));

__device__ __forceinline__ unsigned short f2bf(float x) {
  unsigned int u = __builtin_bit_cast(unsigned int, x);
  u += 0x7FFFu + ((u >> 16) & 1u);  // RNE
  return (unsigned short)(u >> 16);
}

__device__ __forceinline__ unsigned int cvtpk(float lo, float hi) {
  unsigned int r;
  asm("v_cvt_pk_bf16_f32 %0, %1, %2" : "=v"(r) : "v"(lo), "v"(hi));
  return r;
}

__device__ __forceinline__ void gload_lds16(const void* g, void* l) {
  __builtin_amdgcn_global_load_lds(
      (const __attribute__((address_space(1))) uint32_t*)g,
      (__attribute__((address_space(3))) uint32_t*)l, 16, 0, 0);
}

// ---------------- kernel 0: c1/c2[k] = sum_f W[f][k]*a{1,2}[f] ----------------
__global__ void gat_cvec(const float* __restrict__ W, const float* __restrict__ a,
                         float* __restrict__ c1, float* __restrict__ c2) {
  const int k = threadIdx.x;
  float acc1 = 0.f, acc2 = 0.f;
#pragma unroll 8
  for (int f = 0; f < FD; ++f) {
    float w = W[f * FD + k];
    acc1 = fmaf(w, a[f], acc1);
    acc2 = fmaf(w, a[FD + f], acc2);
  }
  c1[k] = acc1;
  c2[k] = acc2;
}

// ---- fused prep: blocks [0,512) wht | [512,2560) svec (pack DELETED) -------
// whTK[ktile(64k)][f(256)][k%64] with the G4 XOR swizzle PRE-APPLIED:
// idx = ktile*16384 + f*64 + ((k>>3)^(f&7))*8 + (k&7).   (rule #21)
__launch_bounds__(256)
__global__ void gat_prep(const float* __restrict__ h, const float* __restrict__ W,
                         const float* __restrict__ c1, const float* __restrict__ c2,
                         unsigned short* __restrict__ whTK,
                         float* __restrict__ s1, float* __restrict__ s2) {
  __shared__ __align__(16) float hT[64][64];
  __shared__ __align__(16) float wT[64][64];
  const int b = blockIdx.x;
  const int t = threadIdx.x;

  if (b < 512) {
    const int i0 = (b & 127) * 64;  // k-range (rows of Wh)
    const int f0 = (b >> 7) * 64;
    const int r = t & 63;
    const int kq = t >> 6;
    const int ty = t >> 4;
    const int tx = t & 15;
    float acc[4][4] = {};
    for (int k0 = 0; k0 < FD; k0 += 64) {
#pragma unroll
      for (int kk = 0; kk < 16; kk += 4) {
        float4 v = *(const float4*)(h + (size_t)(i0 + r) * FD + k0 + kq * 16 + kk);
        hT[kq * 16 + kk + 0][r] = v.x;
        hT[kq * 16 + kk + 1][r] = v.y;
        hT[kq * 16 + kk + 2][r] = v.z;
        hT[kq * 16 + kk + 3][r] = v.w;
        float4 u = *(const float4*)(W + (size_t)(f0 + r) * FD + k0 + kq * 16 + kk);
        wT[kq * 16 + kk + 0][r] = u.x;
        wT[kq * 16 + kk + 1][r] = u.y;
        wT[kq * 16 + kk + 2][r] = u.z;
        wT[kq * 16 + kk + 3][r] = u.w;
      }
      __syncthreads();
#pragma unroll 8
      for (int kk = 0; kk < 64; ++kk) {
        float4 av = *(const float4*)&hT[kk][ty * 4];
        float4 bv = *(const float4*)&wT[kk][tx * 4];
        acc[0][0] = fmaf(av.x, bv.x, acc[0][0]);
        acc[0][1] = fmaf(av.x, bv.y, acc[0][1]);
        acc[0][2] = fmaf(av.x, bv.z, acc[0][2]);
        acc[0][3] = fmaf(av.x, bv.w, acc[0][3]);
        acc[1][0] = fmaf(av.y, bv.x, acc[1][0]);
        acc[1][1] = fmaf(av.y, bv.y, acc[1][1]);
        acc[1][2] = fmaf(av.y, bv.z, acc[1][2]);
        acc[1][3] = fmaf(av.y, bv.w, acc[1][3]);
        acc[2][0] = fmaf(av.z, bv.x, acc[2][0]);
        acc[2][1] = fmaf(av.z, bv.y, acc[2][1]);
        acc[2][2] = fmaf(av.z, bv.z, acc[2][2]);
        acc[2][3] = fmaf(av.z, bv.w, acc[2][3]);
        acc[3][0] = fmaf(av.w, bv.x, acc[3][0]);
        acc[3][1] = fmaf(av.w, bv.y, acc[3][1]);
        acc[3][2] = fmaf(av.w, bv.z, acc[3][2]);
        acc[3][3] = fmaf(av.w, bv.w, acc[3][3]);
      }
      __syncthreads();
    }
    const int iv = i0 + ty * 4;
    const int ktile = iv >> 6;
    const int kl = iv & 63;
#pragma unroll
    for (int j = 0; j < 4; ++j) {
      const int f = f0 + tx * 4 + j;
      ushort4 o;
      o.x = f2bf(acc[0][j]);
      o.y = f2bf(acc[1][j]);
      o.z = f2bf(acc[2][j]);
      o.w = f2bf(acc[3][j]);
      const size_t idx = (size_t)ktile * 16384 + (size_t)f * 64 +
                         (size_t)(((kl >> 3) ^ (f & 7)) * 8 + (kl & 7));
      *(ushort4*)(whTK + idx) = o;
    }
  } else {
    const int i = (b - 512) * 4 + (t >> 6);
    const int lane = t & 63;
    float4 hv = *(const float4*)(h + (size_t)i * FD + lane * 4);
    float4 u = *(const float4*)(c1 + lane * 4);
    float4 v = *(const float4*)(c2 + lane * 4);
    float d1 = hv.x * u.x + hv.y * u.y + hv.z * u.z + hv.w * u.w;
    float d2 = hv.x * v.x + hv.y * v.y + hv.z * v.z + hv.w * v.w;
#pragma unroll
    for (int m = 1; m < 64; m <<= 1) {
      d1 += __shfl_xor(d1, m, 64);
      d2 += __shfl_xor(d2, m, 64);
    }
    if (lane == 0) {
      s1[i] = d1 * LOG2E;
      s2[i] = d2 * LOG2E;
    }
  }
}

// ---- attention: raw-adj fused. 128 rows x 256 f per block, m97-style -------
// grid 512 = 64 rs x 8 kq; block (rs,kq) reads adj[rs*128..)[kq*1024..) --
// each adj element read EXACTLY ONCE device-wide (268 MB stream absorbed into
// the GEMM pipeline; pack kernel deleted). Per iter: [stage B 32KB gload_lds]
// [P-VALU from adj regs -> swizzled As] [reload adj(it+1) -> regs]
// [vmcnt(8)+lgkm(0) raw barrier: B drained, adj left in flight (T4)]
// [64 MFMA/wave] [lgkm(0) raw barrier]. P mapping: wave w rows w*32..+31;
// lane q=lane>>4 row-sub, kx=lane&15 k-chunk; 16 lanes x int4 = 256B/row.
__launch_bounds__(256, 2)
__global__ void gat_attn(const int* __restrict__ adj, const float* __restrict__ s1g,
                         const float* __restrict__ s2g,
                         const unsigned short* __restrict__ whTK,
                         float* __restrict__ accP, float* __restrict__ lP) {
  __shared__ __align__(16) unsigned short Bs[64 * 256];  // [f][k] swz, 32 KB
  __shared__ __align__(16) unsigned short As[128 * 64];  // [row][k] swz, 16 KB
  __shared__ __align__(16) float s2s[1024];              // 4 KB

  const int tid = threadIdx.x;
  const int lane = tid & 63;
  const int w = tid >> 6;
  const int kq = blockIdx.x & 7;
  const int rs = blockIdx.x >> 3;
  const int kbase = kq * 1024;

  // P-phase roles
  const int q = lane >> 4;   // row subgroup 0..3
  const int kx = lane & 15;  // k-chunk (4 ints)
  const int* abase = adj + (size_t)(rs * 128 + w * 32 + q) * NN + kbase + kx * 4;
  float s1v[8];
#pragma unroll
  for (int j = 0; j < 8; ++j) s1v[j] = s1g[rs * 128 + w * 32 + j * 4 + q];

  // MFMA-phase roles
  const int wr = w & 1;
  const int wc = w >> 1;
  const int r16 = lane & 15;
  const int kg = lane >> 4;

  // stage s2 tile (block k-range)
  *(float4*)&s2s[tid * 4] = *(const float4*)(s2g + kbase + tid * 4);

  // prologue: adj(0) into regs
  int4 ca[8];
#pragma unroll
  for (int j = 0; j < 8; ++j) ca[j] = *(const int4*)(abase + (size_t)j * 4 * NN);
  float la[8] = {0.f, 0.f, 0.f, 0.f, 0.f, 0.f, 0.f, 0.f};

  f32x4_t acc[4][8];
  const f32x4_t zero4 = {0.f, 0.f, 0.f, 0.f};
#pragma unroll
  for (int rt = 0; rt < 4; ++rt)
#pragma unroll
    for (int ct = 0; ct < 8; ++ct) acc[rt][ct] = zero4;

  __syncthreads();  // s2s ready (drains prologue vmem too — one-time)

  for (int it = 0; it < 16; ++it) {
    // ---- stage B(it): 32 KB via 8 gload_lds/wave ----
    {
      const char* bsrc = (const char*)whTK + (size_t)(kq * 16 + it) * 32768;
      char* bdst = (char*)Bs;
#pragma unroll
      for (int p = 0; p < 8; ++p)
        gload_lds16(bsrc + w * 8192 + p * 1024 + lane * 16, bdst + w * 8192 + p * 1024);
    }
    __builtin_amdgcn_sched_barrier(0);

    // ---- P-phase from adj regs: 8 rows x 4 ks per thread ----
    {
      float4 s2v = *(const float4*)&s2s[it * 64 + kx * 4];
#pragma unroll
      for (int j = 0; j < 8; ++j) {
        const int4 a = ca[j];
        float x0 = s1v[j] + s2v.x; x0 = fmaxf(x0, SLOPE * x0);
        float x1 = s1v[j] + s2v.y; x1 = fmaxf(x1, SLOPE * x1);
        float x2 = s1v[j] + s2v.z; x2 = fmaxf(x2, SLOPE * x2);
        float x3 = s1v[j] + s2v.w; x3 = fmaxf(x3, SLOPE * x3);
        float p0 = a.x != 0 ? __builtin_amdgcn_exp2f(x0) : 0.f;
        float p1 = a.y != 0 ? __builtin_amdgcn_exp2f(x1) : 0.f;
        float p2 = a.z != 0 ? __builtin_amdgcn_exp2f(x2) : 0.f;
        float p3 = a.w != 0 ? __builtin_amdgcn_exp2f(x3) : 0.f;
        la[j] += (p0 + p1) + (p2 + p3);
        u32x2_t wv;
        wv[0] = cvtpk(p0, p1);
        wv[1] = cvtpk(p2, p3);
        const int row = w * 32 + j * 4 + q;
        *(u32x2_t*)((char*)As + row * 128 + (((kx >> 1) ^ (row & 7)) * 16) + (kx & 1) * 8) = wv;
      }
    }

    // ---- reload adj(it+1) (flies across both barriers; ~700cy to next use) --
    {
      const int itn = (it + 1 < 16) ? it + 1 : it;
#pragma unroll
      for (int j = 0; j < 8; ++j)
        ca[j] = *(const int4*)(abase + (size_t)j * 4 * NN + itn * 64);
    }
    __builtin_amdgcn_sched_barrier(0);

    // ---- barrier-1: B staged (vmcnt(8): 8 adj loads stay in flight), A visible
    asm volatile("s_waitcnt vmcnt(8) lgkmcnt(0)" ::: "memory");
    __builtin_amdgcn_s_barrier();
    __builtin_amdgcn_sched_barrier(0);

    // ---- MFMA phase: 64 MFMA/wave ----
    {
#pragma unroll
      for (int kc = 0; kc < 2; ++kc) {
        const int ch = kc * 4 + kg;
        bf16x8_t a0, a1, a2, a3;
        {
          const int row0 = wr * 64 + r16;
          a0 = *(const bf16x8_t*)((const char*)As + (row0 + 0) * 128 + ((ch ^ ((row0 + 0) & 7)) * 16));
          a1 = *(const bf16x8_t*)((const char*)As + (row0 + 16) * 128 + ((ch ^ ((row0 + 16) & 7)) * 16));
          a2 = *(const bf16x8_t*)((const char*)As + (row0 + 32) * 128 + ((ch ^ ((row0 + 32) & 7)) * 16));
          a3 = *(const bf16x8_t*)((const char*)As + (row0 + 48) * 128 + ((ch ^ ((row0 + 48) & 7)) * 16));
        }
#pragma unroll
        for (int cp = 0; cp < 2; ++cp) {
          bf16x8_t b0, b1, b2, b3;
          {
            const int f0l = wc * 128 + cp * 64 + r16;
            b0 = *(const bf16x8_t*)((const char*)Bs + (f0l + 0) * 128 + ((ch ^ ((f0l + 0) & 7)) * 16));
            b1 = *(const bf16x8_t*)((const char*)Bs + (f0l + 16) * 128 + ((ch ^ ((f0l + 16) & 7)) * 16));
            b2 = *(const bf16x8_t*)((const char*)Bs + (f0l + 32) * 128 + ((ch ^ ((f0l + 32) & 7)) * 16));
            b3 = *(const bf16x8_t*)((const char*)Bs + (f0l + 48) * 128 + ((ch ^ ((f0l + 48) & 7)) * 16));
          }
          const int c0 = cp * 4;
          acc[0][c0 + 0] = __builtin_amdgcn_mfma_f32_16x16x32_bf16(a0, b0, acc[0][c0 + 0], 0, 0, 0);
          acc[0][c0 + 1] = __builtin_amdgcn_mfma_f32_16x16x32_bf16(a0, b1, acc[0][c0 + 1], 0, 0, 0);
          acc[0][c0 + 2] = __builtin_amdgcn_mfma_f32_16x16x32_bf16(a0, b2, acc[0][c0 + 2], 0, 0, 0);
          acc[0][c0 + 3] = __builtin_amdgcn_mfma_f32_16x16x32_bf16(a0, b3, acc[0][c0 + 3], 0, 0, 0);
          acc[1][c0 + 0] = __builtin_amdgcn_mfma_f32_16x16x32_bf16(a1, b0, acc[1][c0 + 0], 0, 0, 0);
          acc[1][c0 + 1] = __builtin_amdgcn_mfma_f32_16x16x32_bf16(a1, b1, acc[1][c0 + 1], 0, 0, 0);
          acc[1][c0 + 2] = __builtin_amdgcn_mfma_f32_16x16x32_bf16(a1, b2, acc[1][c0 + 2], 0, 0, 0);
          acc[1][c0 + 3] = __builtin_amdgcn_mfma_f32_16x16x32_bf16(a1, b3, acc[1][c0 + 3], 0, 0, 0);
          acc[2][c0 + 0] = __builtin_amdgcn_mfma_f32_16x16x32_bf16(a2, b0, acc[2][c0 + 0], 0, 0, 0);
          acc[2][c0 + 1] = __builtin_amdgcn_mfma_f32_16x16x32_bf16(a2, b1, acc[2][c0 + 1], 0, 0, 0);
          acc[2][c0 + 2] = __builtin_amdgcn_mfma_f32_16x16x32_bf16(a2, b2, acc[2][c0 + 2], 0, 0, 0);
          acc[2][c0 + 3] = __builtin_amdgcn_mfma_f32_16x16x32_bf16(a2, b3, acc[2][c0 + 3], 0, 0, 0);
          acc[3][c0 + 0] = __builtin_amdgcn_mfma_f32_16x16x32_bf16(a3, b0, acc[3][c0 + 0], 0, 0, 0);
          acc[3][c0 + 1] = __builtin_amdgcn_mfma_f32_16x16x32_bf16(a3, b1, acc[3][c0 + 1], 0, 0, 0);
          acc[3][c0 + 2] = __builtin_amdgcn_mfma_f32_16x16x32_bf16(a3, b2, acc[3][c0 + 2], 0, 0, 0);
          acc[3][c0 + 3] = __builtin_amdgcn_mfma_f32_16x16x32_bf16(a3, b3, acc[3][c0 + 3], 0, 0, 0);
        }
      }
    }

    // ---- barrier-2: LDS reads retired; adj loads stay in flight ----
    asm volatile("s_waitcnt lgkmcnt(0)" ::: "memory");
    __builtin_amdgcn_s_barrier();
    __builtin_amdgcn_sched_barrier(0);
  }

  // ---- l: reduce each row over its 16 k-chunk lanes, write directly ----
#pragma unroll
  for (int j = 0; j < 8; ++j) {
    float v = la[j];
    v += __shfl_xor(v, 1, 64);
    v += __shfl_xor(v, 2, 64);
    v += __shfl_xor(v, 4, 64);
    v += __shfl_xor(v, 8, 64);
    if ((lane & 15) == 0)
      lP[(size_t)kq * NN + rs * 128 + w * 32 + j * 4 + q] = v;
  }

  // ---- acc partials ----
  float* ap = accP + (size_t)kq * NN * FD;
#pragma unroll
  for (int rt = 0; rt < 4; ++rt) {
#pragma unroll
    for (int ct = 0; ct < 8; ++ct) {
      const int col = wc * 128 + ct * 16 + r16;
#pragma unroll
      for (int g = 0; g < 4; ++g) {
        const int row = rs * 128 + wr * 64 + rt * 16 + kg * 4 + g;
        ap[(size_t)row * FD + col] = acc[rt][ct][g];
      }
    }
  }
}

// ---------------- merge: out[i][f] = sum_kq accP / sum_kq lP -----------------
__global__ void gat_merge(const float* __restrict__ accP, const float* __restrict__ lP,
                          float* __restrict__ out) {
  const int i = blockIdx.x;
  const int f = threadIdx.x;
  float s = 0.f, l = 0.f;
#pragma unroll
  for (int q = 0; q < 8; ++q) {
    s += accP[((size_t)q * NN + i) * FD + f];
    l += lP[(size_t)q * NN + i];
  }
  out[(size_t)i * FD + f] = s / l;
}

extern "C" void kernel_launch(void* const* d_in, const int* in_sizes, int n_in,
                              void* d_out, int out_size, void* d_ws, size_t ws_size,
                              hipStream_t stream) {
  const float* h = (const float*)d_in[0];
  const int* adj = (const int*)d_in[1];
  const float* W = (const float*)d_in[2];
  const float* a = (const float*)d_in[3];
  float* out = (float*)d_out;

  char* ws = (char*)d_ws;
  unsigned short* whTK = (unsigned short*)ws;                // 4 MB
  float* s1 = (float*)(ws + 4194304);                        // 32 KB
  float* s2 = (float*)(ws + 4194304 + 32768);                // 32 KB
  float* c1 = (float*)(ws + 4194304 + 65536);                // 1 KB
  float* c2 = (float*)(ws + 4194304 + 65536 + 1024);         // 1 KB
  float* accP = (float*)(ws + 16777216);                     // 8 x 8 MB
  float* lP = (float*)(ws + 16777216 + 8ull * NN * FD * 4);  // 256 KB

  gat_cvec<<<1, 256, 0, stream>>>(W, a, c1, c2);
  gat_prep<<<2560, 256, 0, stream>>>(h, W, c1, c2, whTK, s1, s2);
  gat_attn<<<512, 256, 0, stream>>>(adj, s1, s2, whTK, accP, lP);
  gat_merge<<<NN, FD, 0, stream>>>(accP, lP, out);
}